// Round 4
// baseline (5253.671 us; speedup 1.0000x reference)
//
#include <hip/hip_runtime.h>
#include <hip/hip_bf16.h>

// Problem constants
#define BB 32
#define NT 64
#define NS 256
#define NN 320      // NT+NS
#define NPS 256
#define DD 768
#define HH 12
#define DHD 64
#define LK 180      // LENS_KEEP
#define NREM 76

// ws layout (float offsets). Lifetimes audited per step; peak = 126.2 MB.
#define OFF_QKV  0LL           // S2-S3: 10240*2304 = 23,592,960
#define OFF_H    23592960LL    // S1-S2: 7,864,320
#define OFF_XA   23592960LL    // S3-S4 (reuse H)
#define OFF_ATP  31457280LL    // S3-S5: 98,304
#define OFF_TOPK 31555584LL    // S5-S7: 5,760 ints
#define OFF_X1   0LL           // S4-S7 (QKV dead)
#define OFF_X2   8000000LL     // S7-S16: 5,996,544
#define OFF_SN   14000000LL    // S8-S9: 4,423,680
#define OFF_QT   0LL           // S9-S12 (X1 dead)
#define OFF_KT   18500000LL    // S10-S12: 6,291,456
#define OFF_VT   24800000LL    // S11-S12: 6,291,456
#define OFF_SA   14000000LL    // S12-S13 (SN dead)
#define OFF_H2   0LL           // S14-S15 (QT dead)
#define OFF_MIDB 18500000LL    // S15-S16: 23,986,176 bf16 (11.99M f-eq)

// d_out (FLOAT32) offsets: (x, git, keep, removed, attn)
#define O_X    0LL
#define O_GIT  5996544LL
#define O_KEEP 5998592LL
#define O_REM  6004352LL
#define O_ATTN 6006784LL

__device__ __forceinline__ float bf2f(unsigned short u) {
  return __uint_as_float((unsigned)u << 16);
}

// ---------------- LayerNorm: rows of 768, one block per row -----------------
__global__ __launch_bounds__(256) void ln_kernel(
    const float* __restrict__ in, float* __restrict__ out,
    const float* __restrict__ g, const float* __restrict__ b,
    int rpb, long long bstride, int row0)
{
  int r = blockIdx.x, t = threadIdx.x;
  long long base = (long long)(r / rpb) * bstride + (long long)(r % rpb + row0) * DD;
  float v0 = in[base + t], v1 = in[base + 256 + t], v2 = in[base + 512 + t];
  __shared__ float red[256];
  red[t] = v0 + v1 + v2;
  __syncthreads();
  #pragma unroll
  for (int off = 128; off > 0; off >>= 1) { if (t < off) red[t] += red[t + off]; __syncthreads(); }
  float mean = red[0] * (1.f / 768.f);
  __syncthreads();
  float d0 = v0 - mean, d1 = v1 - mean, d2 = v2 - mean;
  red[t] = d0 * d0 + d1 * d1 + d2 * d2;
  __syncthreads();
  #pragma unroll
  for (int off = 128; off > 0; off >>= 1) { if (t < off) red[t] += red[t + off]; __syncthreads(); }
  float rstd = rsqrtf(red[0] * (1.f / 768.f) + 1e-5f);
  long long ob = (long long)r * DD;
  out[ob + t]       = d0 * rstd * g[t]       + b[t];
  out[ob + 256 + t] = d1 * rstd * g[256 + t] + b[256 + t];
  out[ob + 512 + t] = d2 * rstd * g[512 + t] + b[512 + t];
}

// -------- Generic GEMM: C[M,N] = act(A[M,K] @ W[K,N] + bias) + resid --------
// A: f32 (abf=0) or bf16 (abf=1, internal mid buffer). W/bias/resid/C: f32.
// C/resid row map: r -> (r/c_rpb)*c_bstride + (r%c_rpb + c_row0)*c_ld.
// Cb (bf16 out) only used for the internal mid buffer.
// Requires M%128==0, N%128==0, K%16==0.
__global__ __launch_bounds__(256) void gemm_k(
    const void* __restrict__ A, int abf, const float* __restrict__ W,
    const float* __restrict__ bias, const float* __restrict__ resid,
    float* __restrict__ Cf, __hip_bfloat16* __restrict__ Cb,
    int M, int N, int K,
    int c_rpb, long long c_bstride, int c_row0, int c_ld, int act)
{
  __shared__ float As[16][132];
  __shared__ float Ws[16][132];
  const float* Af = (const float*)A;
  const unsigned short* Ab = (const unsigned short*)A;
  int t = threadIdx.x;
  long long bm = (long long)blockIdx.y * 128;
  long long bn = (long long)blockIdx.x * 128;
  float acc[8][8] = {};
  int tm = (t >> 4) << 3, tn = (t & 15) << 3;
  for (int k0 = 0; k0 < K; k0 += 16) {
    #pragma unroll
    for (int l = 0; l < 2; ++l) {
      int idx = (t + (l << 8)) << 2;          // 0..2044 step 4
      int m = idx >> 4, kk = idx & 15;        // A tile 128x16
      if (!abf) {
        const float4 a4 = *reinterpret_cast<const float4*>(Af + (bm + m) * K + k0 + kk);
        As[kk + 0][m] = a4.x; As[kk + 1][m] = a4.y; As[kk + 2][m] = a4.z; As[kk + 3][m] = a4.w;
      } else {
        const ushort4 a4 = *reinterpret_cast<const ushort4*>(Ab + (bm + m) * K + k0 + kk);
        As[kk + 0][m] = bf2f(a4.x); As[kk + 1][m] = bf2f(a4.y);
        As[kk + 2][m] = bf2f(a4.z); As[kk + 3][m] = bf2f(a4.w);
      }
      int kw = idx >> 7, n = idx & 127;       // W tile 16x128
      *reinterpret_cast<float4*>(&Ws[kw][n]) =
          *reinterpret_cast<const float4*>(W + (long long)(k0 + kw) * N + bn + n);
    }
    __syncthreads();
    #pragma unroll
    for (int kk = 0; kk < 16; ++kk) {
      float a[8], w[8];
      *reinterpret_cast<float4*>(a)     = *reinterpret_cast<const float4*>(&As[kk][tm]);
      *reinterpret_cast<float4*>(a + 4) = *reinterpret_cast<const float4*>(&As[kk][tm + 4]);
      *reinterpret_cast<float4*>(w)     = *reinterpret_cast<const float4*>(&Ws[kk][tn]);
      *reinterpret_cast<float4*>(w + 4) = *reinterpret_cast<const float4*>(&Ws[kk][tn + 4]);
      #pragma unroll
      for (int i = 0; i < 8; ++i)
        #pragma unroll
        for (int j = 0; j < 8; ++j)
          acc[i][j] = fmaf(a[i], w[j], acc[i][j]);
    }
    __syncthreads();
  }
  #pragma unroll
  for (int i = 0; i < 8; ++i) {
    long long r = bm + tm + i;
    long long crow = (r / c_rpb) * c_bstride + (long long)((int)(r % c_rpb) + c_row0) * c_ld;
    #pragma unroll
    for (int j = 0; j < 8; ++j) {
      long long c = bn + tn + j;
      float v = acc[i][j];
      if (bias) v += bias[c];
      if (act) v = 0.5f * v * (1.f + erff(v * 0.70710678118654752f));  // exact GELU
      if (resid) v += resid[crow + c];
      if (Cf) Cf[crow + c] = v;
      else    Cb[crow + c] = __float2bfloat16(v);
    }
  }
}

// ------------- Generic attention: one block per (b,h), q chunked ------------
// Static LDS (template-sized). K staged f32 (stride 65 -> conflict-free),
// V staged bf16. probs/xa/atp all f32.
template<int TNK>
__global__ __launch_bounds__(256) void attn_kernel(
    const float* __restrict__ qb, int q_rs,
    const float* __restrict__ kb, int k_rs,
    const float* __restrict__ vb, int v_rs,
    float* __restrict__ xab, int xa_rs,
    float* __restrict__ probs, float* __restrict__ atp,
    int NQ, int CH)
{
  __shared__ float ksh[TNK * 65];
  __shared__ __hip_bfloat16 vsh[TNK * 64];
  __shared__ float pss[TNK];
  __shared__ float qrow[64];
  __shared__ float red[256];
  int bh = blockIdx.x; int b = bh / HH, h = bh % HH;
  int t = threadIdx.x;
  for (int i = t; i < TNK * 64; i += 256) {
    int rr = i >> 6, d = i & 63;
    long long gi = (long long)(b * TNK + rr);
    ksh[rr * 65 + d] = kb[gi * k_rs + h * DHD + d];
    vsh[i] = __float2bfloat16(vb[gi * v_rs + h * DHD + d]);
  }
  __syncthreads();
  int q0 = blockIdx.y * CH;
  int q1 = q0 + CH; if (q1 > NQ) q1 = NQ;
  int c0 = t, c1 = t + 256;
  const bool hasC1 = (c1 < TNK);
  float at0 = 0.f, at1 = 0.f;
  for (int q = q0; q < q1; ++q) {
    if (t < 64) qrow[t] = qb[(long long)(b * NQ + q) * q_rs + h * DHD + t];
    __syncthreads();
    float s0, s1 = -3.4e38f;
    {
      const float* kr = ksh + c0 * 65;
      float a0 = 0, a1 = 0, a2 = 0, a3 = 0;
      #pragma unroll
      for (int d = 0; d < 64; d += 4) {
        a0 = fmaf(qrow[d],     kr[d],     a0);
        a1 = fmaf(qrow[d + 1], kr[d + 1], a1);
        a2 = fmaf(qrow[d + 2], kr[d + 2], a2);
        a3 = fmaf(qrow[d + 3], kr[d + 3], a3);
      }
      s0 = ((a0 + a1) + (a2 + a3)) * 0.125f;
    }
    if (hasC1) {
      const float* kr = ksh + c1 * 65;
      float a0 = 0, a1 = 0, a2 = 0, a3 = 0;
      #pragma unroll
      for (int d = 0; d < 64; d += 4) {
        a0 = fmaf(qrow[d],     kr[d],     a0);
        a1 = fmaf(qrow[d + 1], kr[d + 1], a1);
        a2 = fmaf(qrow[d + 2], kr[d + 2], a2);
        a3 = fmaf(qrow[d + 3], kr[d + 3], a3);
      }
      s1 = ((a0 + a1) + (a2 + a3)) * 0.125f;
    }
    red[t] = fmaxf(s0, s1);
    __syncthreads();
    #pragma unroll
    for (int off = 128; off > 0; off >>= 1) { if (t < off) red[t] = fmaxf(red[t], red[t + off]); __syncthreads(); }
    float m = red[0];
    __syncthreads();
    float e0 = expf(s0 - m);
    float e1 = hasC1 ? expf(s1 - m) : 0.f;
    red[t] = e0 + e1;
    __syncthreads();
    #pragma unroll
    for (int off = 128; off > 0; off >>= 1) { if (t < off) red[t] += red[t + off]; __syncthreads(); }
    float ssum = red[0];
    float p0 = e0 / ssum, p1 = e1 / ssum;
    pss[c0] = p0;
    if (hasC1) pss[c1] = p1;
    if (probs) {
      long long pb = ((long long)bh * NQ + q) * TNK;
      probs[pb + c0] = p0;
      if (hasC1) probs[pb + c1] = p1;
    }
    if (atp && q < NT) {
      if (c0 >= NT) at0 += p0;
      if (hasC1)    at1 += p1;
    }
    __syncthreads();
    {
      int d = t & 63, part = t >> 6;
      const int jpp = TNK >> 2;
      int j0 = part * jpp;
      float a0 = 0, a1 = 0, a2 = 0, a3 = 0;
      for (int j = j0; j < j0 + jpp; j += 4) {
        a0 = fmaf(pss[j],     __bfloat162float(vsh[(j)     * 64 + d]), a0);
        a1 = fmaf(pss[j + 1], __bfloat162float(vsh[(j + 1) * 64 + d]), a1);
        a2 = fmaf(pss[j + 2], __bfloat162float(vsh[(j + 2) * 64 + d]), a2);
        a3 = fmaf(pss[j + 3], __bfloat162float(vsh[(j + 3) * 64 + d]), a3);
      }
      red[t] = (a0 + a1) + (a2 + a3);
    }
    __syncthreads();
    if (t < 64) {
      float xv = red[t] + red[64 + t] + red[128 + t] + red[192 + t];
      xab[(long long)(b * NQ + q) * xa_rs + h * DHD + t] = xv;
    }
    __syncthreads();
  }
  if (atp && blockIdx.y == 0) {   // deterministic per-(b,h) partials, no atomics
    if (c0 >= NT) atp[((long long)bh << 8) + c0 - NT] = at0;
    if (hasC1)    atp[((long long)bh << 8) + c1 - NT] = at1;
  }
}

// ---- Per-batch: sum head partials, argsort(-attn_t) stable, emit indices ---
__global__ __launch_bounds__(256) void sort_kernel(
    const float* __restrict__ atp, const int* __restrict__ gis,
    float* __restrict__ keep_out, float* __restrict__ rem_out,
    int* __restrict__ topk)
{
  int b = blockIdx.x, t = threadIdx.x;
  __shared__ float sv[256];
  __shared__ int   si[256];
  float v = 0.f;
  for (int h = 0; h < HH; ++h) v += atp[((long long)(b * HH + h) << 8) + t];
  sv[t] = v; si[t] = t;
  __syncthreads();
  // Bitonic sort: final order = descending value, ties ascending index
  for (int k = 2; k <= 256; k <<= 1) {
    for (int j = k >> 1; j > 0; j >>= 1) {
      int ixj = t ^ j;
      if (ixj > t) {
        float va = sv[t], vb2 = sv[ixj];
        int ia = si[t], ib = si[ixj];
        bool after = (va < vb2) || (va == vb2 && ia > ib);  // t comes after ixj
        bool dirUp = ((t & k) == 0);
        if (after == dirUp) { sv[t] = vb2; sv[ixj] = va; si[t] = ib; si[ixj] = ia; }
      }
      __syncthreads();
    }
  }
  int o = si[t];
  if (t < LK) {
    topk[b * LK + t] = o;
    keep_out[b * LK + t] = (float)gis[(b << 8) + o];
  } else {
    rem_out[b * NREM + (t - LK)] = (float)gis[(b << 8) + o];
  }
}

// ---------------- Gather kept tokens: x2[b, :244] from x1[b, :320] ----------
__global__ __launch_bounds__(256) void gather_kernel(
    const float* __restrict__ x1, const int* __restrict__ topk, float* __restrict__ x2)
{
  int r = blockIdx.x, t = threadIdx.x;
  int b = r / 244, rr = r % 244;
  int src = (rr < NT) ? rr : (NT + topk[b * LK + (rr - NT)]);
  const float* s = x1 + (long long)(b * NN + src) * DD;
  float* d = x2 + (long long)r * DD;
  d[t] = s[t]; d[256 + t] = s[256 + t]; d[512 + t] = s[512 + t];
}

__global__ void git_kernel(const int* __restrict__ git, float* __restrict__ o)
{
  int i = blockIdx.x * 256 + threadIdx.x;
  if (i < BB * NT) o[i] = (float)git[i];
}

extern "C" void kernel_launch(void* const* d_in, const int* in_sizes, int n_in,
                              void* d_out, int out_size, void* d_ws, size_t ws_size,
                              hipStream_t stream) {
  (void)in_sizes; (void)n_in; (void)out_size; (void)ws_size;
  const float* x    = (const float*)d_in[0];
  const float* ps   = (const float*)d_in[1];
  const int*   git  = (const int*)d_in[2];
  const int*   gis  = (const int*)d_in[3];
  const float* g1   = (const float*)d_in[4];
  const float* b1   = (const float*)d_in[5];
  const float* Wqkv = (const float*)d_in[6];
  const float* Wproj= (const float*)d_in[7];
  const float* bproj= (const float*)d_in[8];
  const float* gt   = (const float*)d_in[9];
  const float* bt   = (const float*)d_in[10];
  const float* Wq   = (const float*)d_in[11];
  const float* Wk   = (const float*)d_in[12];
  const float* Wv   = (const float*)d_in[13];
  const float* Wtp  = (const float*)d_in[14];
  const float* btp  = (const float*)d_in[15];
  const float* g2   = (const float*)d_in[16];
  const float* b2   = (const float*)d_in[17];
  const float* W1   = (const float*)d_in[18];
  const float* b1m  = (const float*)d_in[19];
  const float* W2   = (const float*)d_in[20];
  const float* b2m  = (const float*)d_in[21];
  float* wsf = (float*)d_ws;
  float* out = (float*)d_out;

  // 1) h = LN(x)
  hipLaunchKernelGGL(ln_kernel, dim3(BB * NN), dim3(256), 0, stream,
                     x, wsf + OFF_H, g1, b1, BB * NN, 0LL, 0);
  // 2) qkv = h @ Wqkv
  hipLaunchKernelGGL(gemm_k, dim3((3 * DD) / 128, (BB * NN) / 128), dim3(256), 0, stream,
                     (const void*)(wsf + OFF_H), 0, Wqkv,
                     (const float*)nullptr, (const float*)nullptr,
                     wsf + OFF_QKV, (__hip_bfloat16*)nullptr,
                     BB * NN, 3 * DD, DD, BB * NN, 0LL, 0, 3 * DD, 0);
  // 3) stage-1 attention: probs->out (f32), xa->ws, attn_t partials->ws
  hipLaunchKernelGGL((attn_kernel<NN>), dim3(BB * HH, 2), dim3(256), 0, stream,
                     wsf + OFF_QKV, 3 * DD,
                     wsf + OFF_QKV + DD, 3 * DD,
                     wsf + OFF_QKV + 2 * DD, 3 * DD,
                     wsf + OFF_XA, DD,
                     out + O_ATTN, wsf + OFF_ATP, NN, 160);
  // 4) x1 = x + xa @ Wproj + bproj
  hipLaunchKernelGGL(gemm_k, dim3(DD / 128, (BB * NN) / 128), dim3(256), 0, stream,
                     (const void*)(wsf + OFF_XA), 0, Wproj, bproj, x,
                     wsf + OFF_X1, (__hip_bfloat16*)nullptr,
                     BB * NN, DD, DD, BB * NN, 0LL, 0, DD, 0);
  // 5) per-batch argsort of attn_t; emit keep/removed indices (f32)
  hipLaunchKernelGGL(sort_kernel, dim3(BB), dim3(256), 0, stream,
                     wsf + OFF_ATP, gis, out + O_KEEP, out + O_REM,
                     (int*)(wsf + OFF_TOPK));
  // 6) global_index_template passthrough (f32)
  hipLaunchKernelGGL(git_kernel, dim3((BB * NT + 255) / 256), dim3(256), 0, stream,
                     git, out + O_GIT);
  // 7) gather kept tokens -> x2 (B,244,768)
  hipLaunchKernelGGL(gather_kernel, dim3(BB * 244), dim3(256), 0, stream,
                     wsf + OFF_X1, (const int*)(wsf + OFF_TOPK), wsf + OFF_X2);
  // 8) sn = LN(s), s = x2[:,64:]
  hipLaunchKernelGGL(ln_kernel, dim3(BB * LK), dim3(256), 0, stream,
                     wsf + OFF_X2, wsf + OFF_SN, gt, bt, LK, (long long)244 * DD, NT);
  // 9) qT = sn @ Wq ; 10) kT = ps @ Wk ; 11) vT = ps @ Wv
  hipLaunchKernelGGL(gemm_k, dim3(DD / 128, (BB * LK) / 128), dim3(256), 0, stream,
                     (const void*)(wsf + OFF_SN), 0, Wq,
                     (const float*)nullptr, (const float*)nullptr,
                     wsf + OFF_QT, (__hip_bfloat16*)nullptr,
                     BB * LK, DD, DD, BB * LK, 0LL, 0, DD, 0);
  hipLaunchKernelGGL(gemm_k, dim3(DD / 128, (BB * NPS) / 128), dim3(256), 0, stream,
                     (const void*)ps, 0, Wk,
                     (const float*)nullptr, (const float*)nullptr,
                     wsf + OFF_KT, (__hip_bfloat16*)nullptr,
                     BB * NPS, DD, DD, BB * NPS, 0LL, 0, DD, 0);
  hipLaunchKernelGGL(gemm_k, dim3(DD / 128, (BB * NPS) / 128), dim3(256), 0, stream,
                     (const void*)ps, 0, Wv,
                     (const float*)nullptr, (const float*)nullptr,
                     wsf + OFF_VT, (__hip_bfloat16*)nullptr,
                     BB * NPS, DD, DD, BB * NPS, 0LL, 0, DD, 0);
  // 12) stage-2 attention -> sa
  hipLaunchKernelGGL((attn_kernel<NPS>), dim3(BB * HH, 2), dim3(256), 0, stream,
                     wsf + OFF_QT, DD, wsf + OFF_KT, DD, wsf + OFF_VT, DD,
                     wsf + OFF_SA, DD,
                     (float*)nullptr, (float*)nullptr, LK, 90);
  // 13) s2 = s + sa @ Wtp + btp   (written back into x2 rows 64..243)
  hipLaunchKernelGGL(gemm_k, dim3(DD / 128, (BB * LK) / 128), dim3(256), 0, stream,
                     (const void*)(wsf + OFF_SA), 0, Wtp, btp, wsf + OFF_X2,
                     wsf + OFF_X2, (__hip_bfloat16*)nullptr,
                     BB * LK, DD, DD, LK, (long long)244 * DD, NT, DD, 0);
  // 14) h2 = LN(x2)
  hipLaunchKernelGGL(ln_kernel, dim3(BB * 244), dim3(256), 0, stream,
                     wsf + OFF_X2, wsf + OFF_H2, g2, b2, BB * 244, 0LL, 0);
  // 15) mid = gelu(h2 @ W1 + b1m) -> bf16 internal buffer
  hipLaunchKernelGGL(gemm_k, dim3((4 * DD) / 128, (BB * 244) / 128), dim3(256), 0, stream,
                     (const void*)(wsf + OFF_H2), 0, W1, b1m, (const float*)nullptr,
                     (float*)nullptr, (__hip_bfloat16*)(wsf + OFF_MIDB),
                     BB * 244, 4 * DD, DD, BB * 244, 0LL, 0, 4 * DD, 1);
  // 16) x_out = x2 + mid @ W2 + b2m   -> f32 directly into d_out
  hipLaunchKernelGGL(gemm_k, dim3(DD / 128, (BB * 244) / 128), dim3(256), 0, stream,
                     (const void*)(wsf + OFF_MIDB), 1, W2, b2m, wsf + OFF_X2,
                     out + O_X, (__hip_bfloat16*)nullptr,
                     BB * 244, DD, 4 * DD, BB * 244, 0LL, 0, DD, 0);
}

// Round 5
// 3018.585 us; speedup vs baseline: 1.7404x; 1.7404x over previous
//
#include <hip/hip_runtime.h>
#include <hip/hip_bf16.h>

// Problem constants
#define BB 32
#define NT 64
#define NS 256
#define NN 320      // NT+NS
#define NPS 256
#define DD 768
#define HH 12
#define DHD 64
#define LK 180      // LENS_KEEP
#define NREM 76

// ws layout (float offsets). Lifetimes audited per step; peak = 126.2 MB.
#define OFF_QKV  0LL           // S2-S3: 10240*2304 = 23,592,960
#define OFF_H    23592960LL    // S1-S2: 7,864,320
#define OFF_XA   23592960LL    // S3-S4 (reuse H)
#define OFF_ATP  31457280LL    // S3-S5: 98,304 (384 bh x 256)
#define OFF_TOPK 31555584LL    // S5-S7: 5,760 ints
#define OFF_X1   0LL           // S4-S7 (QKV dead)
#define OFF_X2   8000000LL     // S7-S16: 5,996,544
#define OFF_SN   14000000LL    // S8-S9: 4,423,680
#define OFF_QT   0LL           // S9-S12 (X1 dead)
#define OFF_KT   18500000LL    // S10-S12: 6,291,456
#define OFF_VT   24800000LL    // S11-S12: 6,291,456
#define OFF_SA   14000000LL    // S12-S13 (SN dead)
#define OFF_H2   0LL           // S14-S15 (QT dead)
#define OFF_MIDB 18500000LL    // S15-S16: 23,986,176 bf16 (11.99M f-eq)

// d_out (FLOAT32) offsets: (x, git, keep, removed, attn)
#define O_X    0LL
#define O_GIT  5996544LL
#define O_KEEP 5998592LL
#define O_REM  6004352LL
#define O_ATTN 6006784LL

__device__ __forceinline__ float bf2f(unsigned short u) {
  return __uint_as_float((unsigned)u << 16);
}

// ---------------- LayerNorm: rows of 768, one block per row -----------------
__global__ __launch_bounds__(256) void ln_kernel(
    const float* __restrict__ in, float* __restrict__ out,
    const float* __restrict__ g, const float* __restrict__ b,
    int rpb, long long bstride, int row0)
{
  int r = blockIdx.x, t = threadIdx.x;
  long long base = (long long)(r / rpb) * bstride + (long long)(r % rpb + row0) * DD;
  float v0 = in[base + t], v1 = in[base + 256 + t], v2 = in[base + 512 + t];
  __shared__ float red[256];
  red[t] = v0 + v1 + v2;
  __syncthreads();
  #pragma unroll
  for (int off = 128; off > 0; off >>= 1) { if (t < off) red[t] += red[t + off]; __syncthreads(); }
  float mean = red[0] * (1.f / 768.f);
  __syncthreads();
  float d0 = v0 - mean, d1 = v1 - mean, d2 = v2 - mean;
  red[t] = d0 * d0 + d1 * d1 + d2 * d2;
  __syncthreads();
  #pragma unroll
  for (int off = 128; off > 0; off >>= 1) { if (t < off) red[t] += red[t + off]; __syncthreads(); }
  float rstd = rsqrtf(red[0] * (1.f / 768.f) + 1e-5f);
  long long ob = (long long)r * DD;
  out[ob + t]       = d0 * rstd * g[t]       + b[t];
  out[ob + 256 + t] = d1 * rstd * g[256 + t] + b[256 + t];
  out[ob + 512 + t] = d2 * rstd * g[512 + t] + b[512 + t];
}

// -------- Generic GEMM: C[M,N] = act(A[M,K] @ W[K,N] + bias) + resid --------
__global__ __launch_bounds__(256) void gemm_k(
    const void* __restrict__ A, int abf, const float* __restrict__ W,
    const float* __restrict__ bias, const float* __restrict__ resid,
    float* __restrict__ Cf, __hip_bfloat16* __restrict__ Cb,
    int M, int N, int K,
    int c_rpb, long long c_bstride, int c_row0, int c_ld, int act)
{
  __shared__ float As[16][132];
  __shared__ float Ws[16][132];
  const float* Af = (const float*)A;
  const unsigned short* Ab = (const unsigned short*)A;
  int t = threadIdx.x;
  long long bm = (long long)blockIdx.y * 128;
  long long bn = (long long)blockIdx.x * 128;
  float acc[8][8] = {};
  int tm = (t >> 4) << 3, tn = (t & 15) << 3;
  for (int k0 = 0; k0 < K; k0 += 16) {
    #pragma unroll
    for (int l = 0; l < 2; ++l) {
      int idx = (t + (l << 8)) << 2;          // 0..2044 step 4
      int m = idx >> 4, kk = idx & 15;        // A tile 128x16
      if (!abf) {
        const float4 a4 = *reinterpret_cast<const float4*>(Af + (bm + m) * K + k0 + kk);
        As[kk + 0][m] = a4.x; As[kk + 1][m] = a4.y; As[kk + 2][m] = a4.z; As[kk + 3][m] = a4.w;
      } else {
        const ushort4 a4 = *reinterpret_cast<const ushort4*>(Ab + (bm + m) * K + k0 + kk);
        As[kk + 0][m] = bf2f(a4.x); As[kk + 1][m] = bf2f(a4.y);
        As[kk + 2][m] = bf2f(a4.z); As[kk + 3][m] = bf2f(a4.w);
      }
      int kw = idx >> 7, n = idx & 127;       // W tile 16x128
      *reinterpret_cast<float4*>(&Ws[kw][n]) =
          *reinterpret_cast<const float4*>(W + (long long)(k0 + kw) * N + bn + n);
    }
    __syncthreads();
    #pragma unroll
    for (int kk = 0; kk < 16; ++kk) {
      float a[8], w[8];
      *reinterpret_cast<float4*>(a)     = *reinterpret_cast<const float4*>(&As[kk][tm]);
      *reinterpret_cast<float4*>(a + 4) = *reinterpret_cast<const float4*>(&As[kk][tm + 4]);
      *reinterpret_cast<float4*>(w)     = *reinterpret_cast<const float4*>(&Ws[kk][tn]);
      *reinterpret_cast<float4*>(w + 4) = *reinterpret_cast<const float4*>(&Ws[kk][tn + 4]);
      #pragma unroll
      for (int i = 0; i < 8; ++i)
        #pragma unroll
        for (int j = 0; j < 8; ++j)
          acc[i][j] = fmaf(a[i], w[j], acc[i][j]);
    }
    __syncthreads();
  }
  #pragma unroll
  for (int i = 0; i < 8; ++i) {
    long long r = bm + tm + i;
    long long crow = (r / c_rpb) * c_bstride + (long long)((int)(r % c_rpb) + c_row0) * c_ld;
    #pragma unroll
    for (int j = 0; j < 8; ++j) {
      long long c = bn + tn + j;
      float v = acc[i][j];
      if (bias) v += bias[c];
      if (act) v = 0.5f * v * (1.f + erff(v * 0.70710678118654752f));  // exact GELU
      if (resid) v += resid[crow + c];
      if (Cf) Cf[crow + c] = v;
      else    Cb[crow + c] = __float2bfloat16(v);
    }
  }
}

// -------- Attention v2: 1024 threads = 16 waves, one wave per q-row ---------
// K in LDS f32 (pad 65: bank=(lane+d)%32, 2-way free). V in LDS bf16
// TRANSPOSED [d][j] (stride TNK+4). Softmax per-wave via shuffles — no
// barriers in the q loop. attn_t partials reduced across waves at the end.
template<int TNK, int PROBS>
__global__ __launch_bounds__(1024) void attn_fast(
    const float* __restrict__ qb, int q_rs,
    const float* __restrict__ kb, int k_rs,
    const float* __restrict__ vb, int v_rs,
    float* __restrict__ xab, int xa_rs,
    float* __restrict__ probs, float* __restrict__ atp,
    int NQ, int CH)
{
  constexpr int NR  = TNK / 64;      // score cols per lane
  constexpr int VST = TNK + 4;       // transposed V stride (shorts), %4==0
  __shared__ float ksh[TNK * 65];
  __shared__ __hip_bfloat16 vsh[64 * VST];
  __shared__ float pss[16][TNK];
  __shared__ float qsh[16][64];
  int bh = blockIdx.x, b = bh / HH, h = bh % HH;
  int t = threadIdx.x;
  // stage K,V (coalesced global reads; 2-way-free LDS writes)
  for (int i = t; i < TNK * 64; i += 1024) {
    int rr = i >> 6, d = i & 63;
    long long gi = (long long)(b * TNK + rr);
    ksh[rr * 65 + d] = kb[gi * k_rs + h * DHD + d];
    vsh[d * VST + rr] = __float2bfloat16(vb[gi * v_rs + h * DHD + d]);
  }
  __syncthreads();
  int wid = t >> 6, lane = t & 63;
  int q0 = blockIdx.y * CH;
  int q1 = q0 + CH; if (q1 > NQ) q1 = NQ;
  float at[NR > 1 ? NR - 1 : 1] = {};
  for (int q = q0 + wid; q < q1; q += 16) {
    qsh[wid][lane] = qb[(long long)(b * NQ + q) * q_rs + h * DHD + lane];
    float s[NR];
    #pragma unroll
    for (int r = 0; r < NR; ++r) s[r] = 0.f;
    const float* kp = ksh + lane * 65;
    #pragma unroll 16
    for (int d = 0; d < 64; ++d) {
      float qd = qsh[wid][d];
      #pragma unroll
      for (int r = 0; r < NR; ++r)
        s[r] = fmaf(qd, kp[(r << 6) * 65 + d], s[r]);
    }
    float m = -3.4e38f;
    #pragma unroll
    for (int r = 0; r < NR; ++r) { s[r] *= 0.125f; m = fmaxf(m, s[r]); }
    #pragma unroll
    for (int off = 32; off > 0; off >>= 1) m = fmaxf(m, __shfl_xor(m, off));
    float ss = 0.f;
    #pragma unroll
    for (int r = 0; r < NR; ++r) { s[r] = __expf(s[r] - m); ss += s[r]; }
    #pragma unroll
    for (int off = 32; off > 0; off >>= 1) ss += __shfl_xor(ss, off);
    float inv = 1.f / ss;
    long long pb = ((long long)bh * NQ + q) * TNK;
    #pragma unroll
    for (int r = 0; r < NR; ++r) {
      float p = s[r] * inv;
      s[r] = p;
      pss[wid][lane + (r << 6)] = p;
      if (PROBS) probs[pb + lane + (r << 6)] = p;
    }
    if (PROBS && q < NT) {
      #pragma unroll
      for (int r = 1; r < NR; ++r) at[r - 1] += s[r];
    }
    // PV: lane = output dim d; float4 P broadcasts + ushort4 V reads
    float acc = 0.f;
    const __hip_bfloat16* vp = vsh + lane * VST;
    #pragma unroll 8
    for (int j = 0; j < TNK; j += 4) {
      float4 p4 = *reinterpret_cast<const float4*>(&pss[wid][j]);
      ushort4 v4 = *reinterpret_cast<const ushort4*>(&vp[j]);
      acc = fmaf(p4.x, bf2f(v4.x), acc);
      acc = fmaf(p4.y, bf2f(v4.y), acc);
      acc = fmaf(p4.z, bf2f(v4.z), acc);
      acc = fmaf(p4.w, bf2f(v4.w), acc);
    }
    xab[(long long)(b * NQ + q) * xa_rs + h * DHD + lane] = acc;
  }
  if (PROBS) {
    if (blockIdx.y == 0) {   // only chunk 0 holds q < NT
      #pragma unroll
      for (int r = 1; r < NR; ++r) pss[wid][lane + ((r - 1) << 6)] = at[r - 1];
      __syncthreads();
      if (t < 256) {
        float v = 0.f;
        #pragma unroll
        for (int w = 0; w < 16; ++w) v += pss[w][t];
        atp[(long long)bh * 256 + t] = v;   // deterministic, no atomics
      }
    }
  }
}

// ---- Per-batch: sum head partials, argsort(-attn_t) stable, emit indices ---
__global__ __launch_bounds__(256) void sort_kernel(
    const float* __restrict__ atp, const int* __restrict__ gis,
    float* __restrict__ keep_out, float* __restrict__ rem_out,
    int* __restrict__ topk)
{
  int b = blockIdx.x, t = threadIdx.x;
  __shared__ float sv[256];
  __shared__ int   si[256];
  float v = 0.f;
  for (int h = 0; h < HH; ++h) v += atp[((long long)(b * HH + h) << 8) + t];
  sv[t] = v; si[t] = t;
  __syncthreads();
  // Bitonic sort: final order = descending value, ties ascending index
  for (int k = 2; k <= 256; k <<= 1) {
    for (int j = k >> 1; j > 0; j >>= 1) {
      int ixj = t ^ j;
      if (ixj > t) {
        float va = sv[t], vb2 = sv[ixj];
        int ia = si[t], ib = si[ixj];
        bool after = (va < vb2) || (va == vb2 && ia > ib);  // t comes after ixj
        bool dirUp = ((t & k) == 0);
        if (after == dirUp) { sv[t] = vb2; sv[ixj] = va; si[t] = ib; si[ixj] = ia; }
      }
      __syncthreads();
    }
  }
  int o = si[t];
  if (t < LK) {
    topk[b * LK + t] = o;
    keep_out[b * LK + t] = (float)gis[(b << 8) + o];
  } else {
    rem_out[b * NREM + (t - LK)] = (float)gis[(b << 8) + o];
  }
}

// ---------------- Gather kept tokens: x2[b, :244] from x1[b, :320] ----------
__global__ __launch_bounds__(256) void gather_kernel(
    const float* __restrict__ x1, const int* __restrict__ topk, float* __restrict__ x2)
{
  int r = blockIdx.x, t = threadIdx.x;
  int b = r / 244, rr = r % 244;
  int src = (rr < NT) ? rr : (NT + topk[b * LK + (rr - NT)]);
  const float* s = x1 + (long long)(b * NN + src) * DD;
  float* d = x2 + (long long)r * DD;
  d[t] = s[t]; d[256 + t] = s[256 + t]; d[512 + t] = s[512 + t];
}

__global__ void git_kernel(const int* __restrict__ git, float* __restrict__ o)
{
  int i = blockIdx.x * 256 + threadIdx.x;
  if (i < BB * NT) o[i] = (float)git[i];
}

extern "C" void kernel_launch(void* const* d_in, const int* in_sizes, int n_in,
                              void* d_out, int out_size, void* d_ws, size_t ws_size,
                              hipStream_t stream) {
  (void)in_sizes; (void)n_in; (void)out_size; (void)ws_size;
  const float* x    = (const float*)d_in[0];
  const float* ps   = (const float*)d_in[1];
  const int*   git  = (const int*)d_in[2];
  const int*   gis  = (const int*)d_in[3];
  const float* g1   = (const float*)d_in[4];
  const float* b1   = (const float*)d_in[5];
  const float* Wqkv = (const float*)d_in[6];
  const float* Wproj= (const float*)d_in[7];
  const float* bproj= (const float*)d_in[8];
  const float* gt   = (const float*)d_in[9];
  const float* bt   = (const float*)d_in[10];
  const float* Wq   = (const float*)d_in[11];
  const float* Wk   = (const float*)d_in[12];
  const float* Wv   = (const float*)d_in[13];
  const float* Wtp  = (const float*)d_in[14];
  const float* btp  = (const float*)d_in[15];
  const float* g2   = (const float*)d_in[16];
  const float* b2   = (const float*)d_in[17];
  const float* W1   = (const float*)d_in[18];
  const float* b1m  = (const float*)d_in[19];
  const float* W2   = (const float*)d_in[20];
  const float* b2m  = (const float*)d_in[21];
  float* wsf = (float*)d_ws;
  float* out = (float*)d_out;

  // 1) h = LN(x)
  hipLaunchKernelGGL(ln_kernel, dim3(BB * NN), dim3(256), 0, stream,
                     x, wsf + OFF_H, g1, b1, BB * NN, 0LL, 0);
  // 2) qkv = h @ Wqkv
  hipLaunchKernelGGL(gemm_k, dim3((3 * DD) / 128, (BB * NN) / 128), dim3(256), 0, stream,
                     (const void*)(wsf + OFF_H), 0, Wqkv,
                     (const float*)nullptr, (const float*)nullptr,
                     wsf + OFF_QKV, (__hip_bfloat16*)nullptr,
                     BB * NN, 3 * DD, DD, BB * NN, 0LL, 0, 3 * DD, 0);
  // 3) stage-1 attention: probs->out (f32), xa->ws, attn_t partials->ws
  hipLaunchKernelGGL((attn_fast<NN, 1>), dim3(BB * HH, 2), dim3(1024), 0, stream,
                     wsf + OFF_QKV, 3 * DD,
                     wsf + OFF_QKV + DD, 3 * DD,
                     wsf + OFF_QKV + 2 * DD, 3 * DD,
                     wsf + OFF_XA, DD,
                     out + O_ATTN, wsf + OFF_ATP, NN, 160);
  // 4) x1 = x + xa @ Wproj + bproj
  hipLaunchKernelGGL(gemm_k, dim3(DD / 128, (BB * NN) / 128), dim3(256), 0, stream,
                     (const void*)(wsf + OFF_XA), 0, Wproj, bproj, x,
                     wsf + OFF_X1, (__hip_bfloat16*)nullptr,
                     BB * NN, DD, DD, BB * NN, 0LL, 0, DD, 0);
  // 5) per-batch argsort of attn_t; emit keep/removed indices (f32)
  hipLaunchKernelGGL(sort_kernel, dim3(BB), dim3(256), 0, stream,
                     wsf + OFF_ATP, gis, out + O_KEEP, out + O_REM,
                     (int*)(wsf + OFF_TOPK));
  // 6) global_index_template passthrough (f32)
  hipLaunchKernelGGL(git_kernel, dim3((BB * NT + 255) / 256), dim3(256), 0, stream,
                     git, out + O_GIT);
  // 7) gather kept tokens -> x2 (B,244,768)
  hipLaunchKernelGGL(gather_kernel, dim3(BB * 244), dim3(256), 0, stream,
                     wsf + OFF_X1, (const int*)(wsf + OFF_TOPK), wsf + OFF_X2);
  // 8) sn = LN(s), s = x2[:,64:]
  hipLaunchKernelGGL(ln_kernel, dim3(BB * LK), dim3(256), 0, stream,
                     wsf + OFF_X2, wsf + OFF_SN, gt, bt, LK, (long long)244 * DD, NT);
  // 9) qT = sn @ Wq ; 10) kT = ps @ Wk ; 11) vT = ps @ Wv
  hipLaunchKernelGGL(gemm_k, dim3(DD / 128, (BB * LK) / 128), dim3(256), 0, stream,
                     (const void*)(wsf + OFF_SN), 0, Wq,
                     (const float*)nullptr, (const float*)nullptr,
                     wsf + OFF_QT, (__hip_bfloat16*)nullptr,
                     BB * LK, DD, DD, BB * LK, 0LL, 0, DD, 0);
  hipLaunchKernelGGL(gemm_k, dim3(DD / 128, (BB * NPS) / 128), dim3(256), 0, stream,
                     (const void*)ps, 0, Wk,
                     (const float*)nullptr, (const float*)nullptr,
                     wsf + OFF_KT, (__hip_bfloat16*)nullptr,
                     BB * NPS, DD, DD, BB * NPS, 0LL, 0, DD, 0);
  hipLaunchKernelGGL(gemm_k, dim3(DD / 128, (BB * NPS) / 128), dim3(256), 0, stream,
                     (const void*)ps, 0, Wv,
                     (const float*)nullptr, (const float*)nullptr,
                     wsf + OFF_VT, (__hip_bfloat16*)nullptr,
                     BB * NPS, DD, DD, BB * NPS, 0LL, 0, DD, 0);
  // 12) stage-2 attention -> sa
  hipLaunchKernelGGL((attn_fast<NPS, 0>), dim3(BB * HH, 2), dim3(1024), 0, stream,
                     wsf + OFF_QT, DD, wsf + OFF_KT, DD, wsf + OFF_VT, DD,
                     wsf + OFF_SA, DD,
                     (float*)nullptr, (float*)nullptr, LK, 90);
  // 13) s2 = s + sa @ Wtp + btp   (written back into x2 rows 64..243)
  hipLaunchKernelGGL(gemm_k, dim3(DD / 128, (BB * LK) / 128), dim3(256), 0, stream,
                     (const void*)(wsf + OFF_SA), 0, Wtp, btp, wsf + OFF_X2,
                     wsf + OFF_X2, (__hip_bfloat16*)nullptr,
                     BB * LK, DD, DD, LK, (long long)244 * DD, NT, DD, 0);
  // 14) h2 = LN(x2)
  hipLaunchKernelGGL(ln_kernel, dim3(BB * 244), dim3(256), 0, stream,
                     wsf + OFF_X2, wsf + OFF_H2, g2, b2, BB * 244, 0LL, 0);
  // 15) mid = gelu(h2 @ W1 + b1m) -> bf16 internal buffer
  hipLaunchKernelGGL(gemm_k, dim3((4 * DD) / 128, (BB * 244) / 128), dim3(256), 0, stream,
                     (const void*)(wsf + OFF_H2), 0, W1, b1m, (const float*)nullptr,
                     (float*)nullptr, (__hip_bfloat16*)(wsf + OFF_MIDB),
                     BB * 244, 4 * DD, DD, BB * 244, 0LL, 0, 4 * DD, 1);
  // 16) x_out = x2 + mid @ W2 + b2m   -> f32 directly into d_out
  hipLaunchKernelGGL(gemm_k, dim3(DD / 128, (BB * 244) / 128), dim3(256), 0, stream,
                     (const void*)(wsf + OFF_MIDB), 1, W2, b2m, wsf + OFF_X2,
                     out + O_X, (__hip_bfloat16*)nullptr,
                     BB * 244, DD, 4 * DD, BB * 244, 0LL, 0, DD, 0);
}

// Round 7
// 1402.925 us; speedup vs baseline: 3.7448x; 2.1516x over previous
//
#include <hip/hip_runtime.h>
#include <hip/hip_bf16.h>

// Problem constants
#define BB 32
#define NT 64
#define NS 256
#define NN 320
#define NPS 256
#define DD 768
#define HH 12
#define DHD 64
#define LK 180
#define NREM 76

// ws layout (float-element offsets). Peak 29,479,648 f = 117.9 MB (< proven 126.2).
#define OFF_QK    0LL          // f32 [10240][1536]  S2-S3
#define OFF_VB    15728640LL   // bf16[10240][768]   S2b-S3
#define OFF_HF    19660800LL   // f32 [10240][768]   S1-S2b
#define OFF_WQVT  27525120LL   // bf16[768][768]     S0-S2b (ends 27,820,032)
#define OFF_ATP   27820032LL   // f32 384*256        S3-S5  (ends 27,918,336)
#define OFF_TOPK  27918336LL   // int 5760           S5-S7
#define OFF_XA    19660800LL   // bf16[10240][768]   S3-S4 (HF dead)
#define OFF_X1    0LL          // f32 [10240][768]   S4-S7 (QK dead)
#define OFF_X2    8000000LL    // f32 [7808][768]    S7-S16
#define OFF_SN    14000000LL   // bf16[5760][768]    S8-S9
#define OFF_PSB   16250000LL   // bf16[8192][768]    S8b-S11
#define OFF_QT    0LL          // bf16[5760][768]    S9-S12 (X1 dead)
#define OFF_KT    19400000LL   // bf16[8192][768]    S10-S12
#define OFF_VT    22600000LL   // bf16[8192][768]    S11-S12 (ends 25,745,728)
#define OFF_WTS   25800000LL   // bf16[768][768] serial small-W slot S4-S13
#define OFF_SA    14000000LL   // bf16[5760][768]    S12-S13 (SN dead)
#define OFF_H2    0LL          // bf16[7808][768]    S14-S15 (QT dead)
#define OFF_MIDB  16250000LL   // bf16[7808][3072]   S15-S16 (ends 28,243,088)
#define OFF_WTS2  28300000LL   // bf16 W1t/W2t slot  S15-S16 (ends 29,479,648)

// d_out (f32) offsets: (x, git, keep, removed, attn)
#define O_X    0LL
#define O_GIT  5996544LL
#define O_KEEP 5998592LL
#define O_REM  6004352LL
#define O_ATTN 6006784LL

typedef __attribute__((ext_vector_type(8))) short short8v;
typedef __attribute__((ext_vector_type(4))) float f32x4;

__device__ __forceinline__ float bf2f(unsigned short u) {
  return __uint_as_float((unsigned)u << 16);
}
__device__ __forceinline__ unsigned short f2bfu(float f) {
  __hip_bfloat16 h = __float2bfloat16(f);
  return *reinterpret_cast<unsigned short*>(&h);
}

// ---------------- LayerNorm. OMODE: 0=f32, 1=bf16, 3=f32+bf16 ---------------
template<int OMODE>
__global__ __launch_bounds__(256) void ln_kernel(
    const float* __restrict__ in, float* __restrict__ outf,
    unsigned short* __restrict__ outh,
    const float* __restrict__ g, const float* __restrict__ b,
    int rpb, long long bstride, int row0)
{
  int r = blockIdx.x, t = threadIdx.x;
  long long base = (long long)(r / rpb) * bstride + (long long)(r % rpb + row0) * DD;
  float v0 = in[base + t], v1 = in[base + 256 + t], v2 = in[base + 512 + t];
  __shared__ float red[256];
  red[t] = v0 + v1 + v2;
  __syncthreads();
  #pragma unroll
  for (int off = 128; off > 0; off >>= 1) { if (t < off) red[t] += red[t + off]; __syncthreads(); }
  float mean = red[0] * (1.f / 768.f);
  __syncthreads();
  float d0 = v0 - mean, d1 = v1 - mean, d2 = v2 - mean;
  red[t] = d0 * d0 + d1 * d1 + d2 * d2;
  __syncthreads();
  #pragma unroll
  for (int off = 128; off > 0; off >>= 1) { if (t < off) red[t] += red[t + off]; __syncthreads(); }
  float rstd = rsqrtf(red[0] * (1.f / 768.f) + 1e-5f);
  long long ob = (long long)r * DD;
  float o0 = d0 * rstd * g[t]       + b[t];
  float o1 = d1 * rstd * g[256 + t] + b[256 + t];
  float o2 = d2 * rstd * g[512 + t] + b[512 + t];
  if (OMODE == 0 || OMODE == 3) {
    outf[ob + t] = o0; outf[ob + 256 + t] = o1; outf[ob + 512 + t] = o2;
  }
  if (OMODE == 1 || OMODE == 3) {
    outh[ob + t] = f2bfu(o0); outh[ob + 256 + t] = f2bfu(o1); outh[ob + 512 + t] = f2bfu(o2);
  }
}

// ------ Transpose+convert: W f32 [K][Nfull] cols [n0off..) -> bf16 [N][K] ---
__global__ __launch_bounds__(256) void cvt_wt(
    const float* __restrict__ W, unsigned short* __restrict__ Th,
    int K, int Nfull, int n0off)
{
  __shared__ float tile[32][33];
  int n0 = blockIdx.x * 32, k0 = blockIdx.y * 32;
  int tx = threadIdx.x & 31, ty4 = (threadIdx.x >> 5) * 4;
  #pragma unroll
  for (int i = 0; i < 4; ++i)
    tile[ty4 + i][tx] = W[(long long)(k0 + ty4 + i) * Nfull + n0off + n0 + tx];
  __syncthreads();
  #pragma unroll
  for (int i = 0; i < 4; ++i)
    Th[(long long)(n0 + ty4 + i) * K + k0 + tx] = f2bfu(tile[tx][ty4 + i]);
}

// ---------------- f32 -> bf16 copy (vectorized) -----------------------------
__global__ __launch_bounds__(256) void cvt_bf_kernel(
    const float* __restrict__ in, unsigned short* __restrict__ out, long long n)
{
  long long i = ((long long)blockIdx.x * 256 + threadIdx.x) * 4;
  if (i < n) {
    float4 v = *reinterpret_cast<const float4*>(&in[i]);
    ushort4 o;
    o.x = f2bfu(v.x); o.y = f2bfu(v.y); o.z = f2bfu(v.z); o.w = f2bfu(v.w);
    *reinterpret_cast<ushort4*>(&out[i]) = o;
  }
}

// -------- f32 vector GEMM (order-critical path): C = A @ W + ... ------------
// W stride wst (may exceed computed cols). Per-wave 8x8 lane grid: LDS b128
// reads span 64 words -> 2-way conflicts (free) instead of 4-way.
__global__ __launch_bounds__(256) void gemm_k(
    const float* __restrict__ A, const float* __restrict__ W, int wst,
    float* __restrict__ Cf, int c_ld, int M, int K)
{
  __shared__ float As[16][132];
  __shared__ float Ws[16][132];
  int t = threadIdx.x;
  long long bm = (long long)blockIdx.y * 128;
  long long bn = (long long)blockIdx.x * 128;
  float acc[8][8] = {};
  int wid = t >> 6, lane = t & 63;
  int tm = ((wid >> 1) << 6) + ((lane >> 3) << 3);
  int tn = ((wid & 1) << 6) + ((lane & 7) << 3);
  for (int k0 = 0; k0 < K; k0 += 16) {
    #pragma unroll
    for (int l = 0; l < 2; ++l) {
      int idx = (t + (l << 8)) << 2;
      int m = idx >> 4, kk = idx & 15;
      const float4 a4 = *reinterpret_cast<const float4*>(A + (bm + m) * K + k0 + kk);
      As[kk + 0][m] = a4.x; As[kk + 1][m] = a4.y; As[kk + 2][m] = a4.z; As[kk + 3][m] = a4.w;
      int kw = idx >> 7, n = idx & 127;
      *reinterpret_cast<float4*>(&Ws[kw][n]) =
          *reinterpret_cast<const float4*>(W + (long long)(k0 + kw) * wst + bn + n);
    }
    __syncthreads();
    #pragma unroll
    for (int kk = 0; kk < 16; ++kk) {
      float a[8], w[8];
      *reinterpret_cast<float4*>(a)     = *reinterpret_cast<const float4*>(&As[kk][tm]);
      *reinterpret_cast<float4*>(a + 4) = *reinterpret_cast<const float4*>(&As[kk][tm + 4]);
      *reinterpret_cast<float4*>(w)     = *reinterpret_cast<const float4*>(&Ws[kk][tn]);
      *reinterpret_cast<float4*>(w + 4) = *reinterpret_cast<const float4*>(&Ws[kk][tn + 4]);
      #pragma unroll
      for (int i = 0; i < 8; ++i)
        #pragma unroll
        for (int j = 0; j < 8; ++j)
          acc[i][j] = fmaf(a[i], w[j], acc[i][j]);
    }
    __syncthreads();
  }
  #pragma unroll
  for (int i = 0; i < 8; ++i) {
    long long crow = (bm + tm + i) * c_ld;
    #pragma unroll
    for (int j = 0; j < 8; ++j)
      Cf[crow + bn + tn + j] = acc[i][j];
  }
}

// -------- MFMA GEMM: C[M,N] = act(A[M,K] @ Bt[N,K]^T + bias) + resid --------
// A bf16 (AF32=0) or f32-converted-in-staging (AF32=1). Bt = pre-transposed
// bf16 weights [N][K]. Out: f32 Cf (rowmap) if colsplit>0 else bf16 Cb.
template<int AF32>
__global__ __launch_bounds__(256) void gemm_mfma(
    const void* __restrict__ A, const unsigned short* __restrict__ Bt,
    const float* __restrict__ bias, const float* __restrict__ resid,
    float* __restrict__ Cf, int ldf,
    unsigned short* __restrict__ Cb, int ldb, int colsplit,
    int M, int N, int K,
    int c_rpb, long long c_bstride, int c_row0, int act)
{
  __shared__ unsigned short As[128 * 40], Bs[128 * 40];
  const unsigned short* Ab = (const unsigned short*)A;
  const float* Af = (const float*)A;
  int t = threadIdx.x;
  long long bm = (long long)blockIdx.y * 128;
  long long bn = (long long)blockIdx.x * 128;
  int wid = t >> 6, lane = t & 63;
  int wr = (wid >> 1) << 6, wc = (wid & 1) << 6;
  f32x4 acc[4][4];
  #pragma unroll
  for (int m = 0; m < 4; ++m)
    #pragma unroll
    for (int n = 0; n < 4; ++n) acc[m][n] = (f32x4){0.f, 0.f, 0.f, 0.f};
  for (int k0 = 0; k0 < K; k0 += 32) {
    #pragma unroll
    for (int l = 0; l < 2; ++l) {
      int e = (t + (l << 8)) << 3;
      int row = e >> 5, kk = e & 31;
      int ls = row * 40 + kk;
      if (AF32) {
        const float4 f0 = *reinterpret_cast<const float4*>(&Af[(bm + row) * K + k0 + kk]);
        const float4 f1 = *reinterpret_cast<const float4*>(&Af[(bm + row) * K + k0 + kk + 4]);
        ushort4 u0, u1;
        u0.x = f2bfu(f0.x); u0.y = f2bfu(f0.y); u0.z = f2bfu(f0.z); u0.w = f2bfu(f0.w);
        u1.x = f2bfu(f1.x); u1.y = f2bfu(f1.y); u1.z = f2bfu(f1.z); u1.w = f2bfu(f1.w);
        *reinterpret_cast<ushort4*>(&As[ls])     = u0;
        *reinterpret_cast<ushort4*>(&As[ls + 4]) = u1;
      } else {
        *reinterpret_cast<int4*>(&As[ls]) = *reinterpret_cast<const int4*>(&Ab[(bm + row) * K + k0 + kk]);
      }
      *reinterpret_cast<int4*>(&Bs[ls]) = *reinterpret_cast<const int4*>(&Bt[(bn + row) * K + k0 + kk]);
    }
    __syncthreads();
    int ra = (wr + (lane & 15)) * 40 + ((lane >> 4) << 3);
    int rb = (wc + (lane & 15)) * 40 + ((lane >> 4) << 3);
    short8v a[4], b[4];
    #pragma unroll
    for (int m = 0; m < 4; ++m) {
      a[m] = *reinterpret_cast<const short8v*>(&As[ra + m * 16 * 40]);
      b[m] = *reinterpret_cast<const short8v*>(&Bs[rb + m * 16 * 40]);
    }
    #pragma unroll
    for (int m = 0; m < 4; ++m)
      #pragma unroll
      for (int n = 0; n < 4; ++n)
        acc[m][n] = __builtin_amdgcn_mfma_f32_16x16x32_bf16(a[m], b[n], acc[m][n], 0, 0, 0);
    __syncthreads();
  }
  int ro = (lane >> 4) << 2, co = lane & 15;
  #pragma unroll
  for (int m = 0; m < 4; ++m) {
    #pragma unroll
    for (int j = 0; j < 4; ++j) {
      long long r = bm + wr + m * 16 + ro + j;
      long long base = (r / c_rpb) * c_bstride + (long long)((int)(r % c_rpb) + c_row0) * ldf;
      #pragma unroll
      for (int n = 0; n < 4; ++n) {
        long long c = bn + wc + n * 16 + co;
        float v = acc[m][n][j];
        if (bias) v += bias[c];
        if (act) v = 0.5f * v * (1.f + erff(v * 0.70710678118654752f));
        if (resid) v += resid[base + c];
        if (c < colsplit) Cf[base + c] = v;
        else Cb[r * ldb + (c - colsplit)] = f2bfu(v);
      }
    }
  }
}

// -------- Attention: 16 waves, one wave per q-row; f32 or bf16 operands -----
template<int TNK, int PROBS, int QKBF, int VBF>
__global__ __launch_bounds__(1024) void attn_fast(
    const void* __restrict__ qb, int q_rs,
    const void* __restrict__ kb, int k_rs,
    const void* __restrict__ vb, int v_rs,
    unsigned short* __restrict__ xab, int xa_rs,
    float* __restrict__ probs, float* __restrict__ atp,
    int NQ, int CH)
{
  constexpr int NR  = TNK / 64;
  constexpr int VST = TNK + 4;
  __shared__ float ksh[TNK * 65];
  __shared__ unsigned short vsh[64 * VST];
  __shared__ float pss[16][TNK];
  __shared__ float qsh[16][64];
  int bh = blockIdx.x, b = bh / HH, h = bh % HH;
  int t = threadIdx.x;
  const float* kf = (const float*)kb;
  const unsigned short* ku = (const unsigned short*)kb;
  const float* vf = (const float*)vb;
  const unsigned short* vu = (const unsigned short*)vb;
  const float* qf = (const float*)qb;
  const unsigned short* qu = (const unsigned short*)qb;
  for (int i = t; i < TNK * 64; i += 1024) {
    int rr = i >> 6, d = i & 63;
    long long gi = (long long)(b * TNK + rr);
    ksh[rr * 65 + d] = QKBF ? bf2f(ku[gi * k_rs + h * DHD + d]) : kf[gi * k_rs + h * DHD + d];
    vsh[d * VST + rr] = VBF ? vu[gi * v_rs + h * DHD + d] : f2bfu(vf[gi * v_rs + h * DHD + d]);
  }
  __syncthreads();
  int wid = t >> 6, lane = t & 63;
  int q0 = blockIdx.y * CH;
  int q1 = q0 + CH; if (q1 > NQ) q1 = NQ;
  float at[NR > 1 ? NR - 1 : 1] = {};
  for (int q = q0 + wid; q < q1; q += 16) {
    long long qi = (long long)(b * NQ + q) * q_rs + h * DHD + lane;
    qsh[wid][lane] = QKBF ? bf2f(qu[qi]) : qf[qi];
    float s[NR];
    #pragma unroll
    for (int r = 0; r < NR; ++r) s[r] = 0.f;
    const float* kp = ksh + lane * 65;
    #pragma unroll 16
    for (int d = 0; d < 64; ++d) {
      float qd = qsh[wid][d];
      #pragma unroll
      for (int r = 0; r < NR; ++r)
        s[r] = fmaf(qd, kp[(r << 6) * 65 + d], s[r]);
    }
    float m = -3.4e38f;
    #pragma unroll
    for (int r = 0; r < NR; ++r) { s[r] *= 0.125f; m = fmaxf(m, s[r]); }
    #pragma unroll
    for (int off = 32; off > 0; off >>= 1) m = fmaxf(m, __shfl_xor(m, off));
    float ss = 0.f;
    #pragma unroll
    for (int r = 0; r < NR; ++r) { s[r] = __expf(s[r] - m); ss += s[r]; }
    #pragma unroll
    for (int off = 32; off > 0; off >>= 1) ss += __shfl_xor(ss, off);
    float inv = 1.f / ss;
    long long pb = ((long long)bh * NQ + q) * TNK;
    #pragma unroll
    for (int r = 0; r < NR; ++r) {
      float p = s[r] * inv;
      s[r] = p;
      pss[wid][lane + (r << 6)] = p;
      if (PROBS) probs[pb + lane + (r << 6)] = p;
    }
    if (PROBS && q < NT) {
      #pragma unroll
      for (int r = 1; r < NR; ++r) at[r - 1] += s[r];
    }
    float acc = 0.f;
    const unsigned short* vp = vsh + lane * VST;
    #pragma unroll 8
    for (int j = 0; j < TNK; j += 4) {
      float4 p4 = *reinterpret_cast<const float4*>(&pss[wid][j]);
      ushort4 v4 = *reinterpret_cast<const ushort4*>(&vp[j]);
      acc = fmaf(p4.x, bf2f(v4.x), acc);
      acc = fmaf(p4.y, bf2f(v4.y), acc);
      acc = fmaf(p4.z, bf2f(v4.z), acc);
      acc = fmaf(p4.w, bf2f(v4.w), acc);
    }
    xab[(long long)(b * NQ + q) * xa_rs + h * DHD + lane] = f2bfu(acc);
  }
  if (PROBS) {
    if (blockIdx.y == 0) {
      #pragma unroll
      for (int r = 1; r < NR; ++r) pss[wid][lane + ((r - 1) << 6)] = at[r - 1];
      __syncthreads();
      if (t < 256) {
        float v = 0.f;
        #pragma unroll
        for (int w = 0; w < 16; ++w) v += pss[w][t];
        atp[(long long)bh * 256 + t] = v;
      }
    }
  }
}

// ---- Per-batch: sum head partials, argsort(-attn_t) stable, emit indices ---
__global__ __launch_bounds__(256) void sort_kernel(
    const float* __restrict__ atp, const int* __restrict__ gis,
    float* __restrict__ keep_out, float* __restrict__ rem_out,
    int* __restrict__ topk)
{
  int b = blockIdx.x, t = threadIdx.x;
  __shared__ float sv[256];
  __shared__ int   si[256];
  float v = 0.f;
  for (int h = 0; h < HH; ++h) v += atp[((long long)(b * HH + h) << 8) + t];
  sv[t] = v; si[t] = t;
  __syncthreads();
  for (int k = 2; k <= 256; k <<= 1) {
    for (int j = k >> 1; j > 0; j >>= 1) {
      int ixj = t ^ j;
      if (ixj > t) {
        float va = sv[t], vb2 = sv[ixj];
        int ia = si[t], ib = si[ixj];
        bool after = (va < vb2) || (va == vb2 && ia > ib);
        bool dirUp = ((t & k) == 0);
        if (after == dirUp) { sv[t] = vb2; sv[ixj] = va; si[t] = ib; si[ixj] = ia; }
      }
      __syncthreads();
    }
  }
  int o = si[t];
  if (t < LK) {
    topk[b * LK + t] = o;
    keep_out[b * LK + t] = (float)gis[(b << 8) + o];
  } else {
    rem_out[b * NREM + (t - LK)] = (float)gis[(b << 8) + o];
  }
}

// ---------------- Gather kept tokens: x2[b, :244] from x1[b, :320] ----------
__global__ __launch_bounds__(256) void gather_kernel(
    const float* __restrict__ x1, const int* __restrict__ topk, float* __restrict__ x2)
{
  int r = blockIdx.x, t = threadIdx.x;
  int b = r / 244, rr = r % 244;
  int src = (rr < NT) ? rr : (NT + topk[b * LK + (rr - NT)]);
  const float* s = x1 + (long long)(b * NN + src) * DD;
  float* d = x2 + (long long)r * DD;
  d[t] = s[t]; d[256 + t] = s[256 + t]; d[512 + t] = s[512 + t];
}

__global__ void git_kernel(const int* __restrict__ git, float* __restrict__ o)
{
  int i = blockIdx.x * 256 + threadIdx.x;
  if (i < BB * NT) o[i] = (float)git[i];
}

extern "C" void kernel_launch(void* const* d_in, const int* in_sizes, int n_in,
                              void* d_out, int out_size, void* d_ws, size_t ws_size,
                              hipStream_t stream) {
  (void)in_sizes; (void)n_in; (void)out_size; (void)ws_size;
  const float* x    = (const float*)d_in[0];
  const float* ps   = (const float*)d_in[1];
  const int*   git  = (const int*)d_in[2];
  const int*   gis  = (const int*)d_in[3];
  const float* g1   = (const float*)d_in[4];
  const float* b1   = (const float*)d_in[5];
  const float* Wqkv = (const float*)d_in[6];
  const float* Wproj= (const float*)d_in[7];
  const float* bproj= (const float*)d_in[8];
  const float* gt   = (const float*)d_in[9];
  const float* bt   = (const float*)d_in[10];
  const float* Wq   = (const float*)d_in[11];
  const float* Wk   = (const float*)d_in[12];
  const float* Wv   = (const float*)d_in[13];
  const float* Wtp  = (const float*)d_in[14];
  const float* btp  = (const float*)d_in[15];
  const float* g2   = (const float*)d_in[16];
  const float* b2   = (const float*)d_in[17];
  const float* W1   = (const float*)d_in[18];
  const float* b1m  = (const float*)d_in[19];
  const float* W2   = (const float*)d_in[20];
  const float* b2m  = (const float*)d_in[21];
  float* wsf = (float*)d_ws;
  float* out = (float*)d_out;
  unsigned short* VBp  = (unsigned short*)(wsf + OFF_VB);
  unsigned short* WQVT = (unsigned short*)(wsf + OFF_WQVT);
  unsigned short* XAp  = (unsigned short*)(wsf + OFF_XA);
  unsigned short* WTS  = (unsigned short*)(wsf + OFF_WTS);
  unsigned short* WTS2 = (unsigned short*)(wsf + OFF_WTS2);
  unsigned short* SNp  = (unsigned short*)(wsf + OFF_SN);
  unsigned short* QTp  = (unsigned short*)(wsf + OFF_QT);
  unsigned short* PSBp = (unsigned short*)(wsf + OFF_PSB);
  unsigned short* KTp  = (unsigned short*)(wsf + OFF_KT);
  unsigned short* VTp  = (unsigned short*)(wsf + OFF_VT);
  unsigned short* SAp  = (unsigned short*)(wsf + OFF_SA);
  unsigned short* H2p  = (unsigned short*)(wsf + OFF_H2);
  unsigned short* MIDp = (unsigned short*)(wsf + OFF_MIDB);

  // S0: Wqkv v-part -> transposed bf16 [768][768]
  hipLaunchKernelGGL(cvt_wt, dim3(768 / 32, 768 / 32), dim3(256), 0, stream,
                     Wqkv, WQVT, DD, 3 * DD, 1536);
  // S1: h = LN(x) -> f32 HF (order-critical; bf16 copy not needed: v uses AF32)
  hipLaunchKernelGGL((ln_kernel<0>), dim3(BB * NN), dim3(256), 0, stream,
                     x, wsf + OFF_HF, (unsigned short*)nullptr, g1, b1, BB * NN, 0LL, 0);
  // S2a: qk = h @ Wqkv[:, :1536]  (f32 vector GEMM, round-5-exact numerics)
  hipLaunchKernelGGL(gemm_k, dim3(1536 / 128, (BB * NN) / 128), dim3(256), 0, stream,
                     wsf + OFF_HF, Wqkv, 3 * DD, wsf + OFF_QK, 1536, BB * NN, DD);
  // S2b: v = h @ Wqkv[:, 1536:]  (MFMA bf16, f32 A converted in staging)
  hipLaunchKernelGGL((gemm_mfma<1>), dim3(768 / 128, (BB * NN) / 128), dim3(256), 0, stream,
                     (const void*)(wsf + OFF_HF), WQVT, (const float*)nullptr, (const float*)nullptr,
                     (float*)nullptr, 1, VBp, DD, 0,
                     BB * NN, DD, DD, BB * NN, 0LL, 0, 0);
  // S3: stage-1 attention (f32 q,k; bf16 v) -> probs f32, xa bf16, atp
  hipLaunchKernelGGL((attn_fast<NN, 1, 0, 1>), dim3(BB * HH, 2), dim3(1024), 0, stream,
                     (const void*)(wsf + OFF_QK), 1536,
                     (const void*)(wsf + OFF_QK + 768), 1536,
                     (const void*)VBp, DD,
                     XAp, DD, out + O_ATTN, wsf + OFF_ATP, NN, 160);
  // S4: x1 = x + xa @ Wproj + bproj (MFMA)
  hipLaunchKernelGGL(cvt_wt, dim3(768 / 32, 768 / 32), dim3(256), 0, stream,
                     Wproj, WTS, DD, DD, 0);
  hipLaunchKernelGGL((gemm_mfma<0>), dim3(768 / 128, (BB * NN) / 128), dim3(256), 0, stream,
                     (const void*)XAp, WTS, bproj, x,
                     wsf + OFF_X1, DD, (unsigned short*)nullptr, 1, DD,
                     BB * NN, DD, DD, BB * NN, 0LL, 0, 0);
  // S5: argsort attn_t
  hipLaunchKernelGGL(sort_kernel, dim3(BB), dim3(256), 0, stream,
                     wsf + OFF_ATP, gis, out + O_KEEP, out + O_REM,
                     (int*)(wsf + OFF_TOPK));
  // S6: git passthrough
  hipLaunchKernelGGL(git_kernel, dim3((BB * NT + 255) / 256), dim3(256), 0, stream,
                     git, out + O_GIT);
  // S7: gather -> x2 f32
  hipLaunchKernelGGL(gather_kernel, dim3(BB * 244), dim3(256), 0, stream,
                     wsf + OFF_X1, (const int*)(wsf + OFF_TOPK), wsf + OFF_X2);
  // S8: sn = LN(s) -> bf16
  hipLaunchKernelGGL((ln_kernel<1>), dim3(BB * LK), dim3(256), 0, stream,
                     wsf + OFF_X2, (float*)nullptr, SNp, gt, bt, LK, (long long)244 * DD, NT);
  // S8b: ps -> bf16
  hipLaunchKernelGGL(cvt_bf_kernel, dim3(6144), dim3(256), 0, stream,
                     ps, PSBp, (long long)BB * NPS * DD);
  // S9: qT = sn @ Wq (MFMA -> bf16)
  hipLaunchKernelGGL(cvt_wt, dim3(768 / 32, 768 / 32), dim3(256), 0, stream,
                     Wq, WTS, DD, DD, 0);
  hipLaunchKernelGGL((gemm_mfma<0>), dim3(768 / 128, (BB * LK) / 128), dim3(256), 0, stream,
                     (const void*)SNp, WTS, (const float*)nullptr, (const float*)nullptr,
                     (float*)nullptr, 1, QTp, DD, 0,
                     BB * LK, DD, DD, BB * LK, 0LL, 0, 0);
  // S10: kT = ps @ Wk
  hipLaunchKernelGGL(cvt_wt, dim3(768 / 32, 768 / 32), dim3(256), 0, stream,
                     Wk, WTS, DD, DD, 0);
  hipLaunchKernelGGL((gemm_mfma<0>), dim3(768 / 128, (BB * NPS) / 128), dim3(256), 0, stream,
                     (const void*)PSBp, WTS, (const float*)nullptr, (const float*)nullptr,
                     (float*)nullptr, 1, KTp, DD, 0,
                     BB * NPS, DD, DD, BB * NPS, 0LL, 0, 0);
  // S11: vT = ps @ Wv
  hipLaunchKernelGGL(cvt_wt, dim3(768 / 32, 768 / 32), dim3(256), 0, stream,
                     Wv, WTS, DD, DD, 0);
  hipLaunchKernelGGL((gemm_mfma<0>), dim3(768 / 128, (BB * NPS) / 128), dim3(256), 0, stream,
                     (const void*)PSBp, WTS, (const float*)nullptr, (const float*)nullptr,
                     (float*)nullptr, 1, VTp, DD, 0,
                     BB * NPS, DD, DD, BB * NPS, 0LL, 0, 0);
  // S12: stage-2 attention (all bf16) -> sa bf16
  hipLaunchKernelGGL((attn_fast<NPS, 0, 1, 1>), dim3(BB * HH, 2), dim3(1024), 0, stream,
                     (const void*)QTp, DD, (const void*)KTp, DD, (const void*)VTp, DD,
                     SAp, DD, (float*)nullptr, (float*)nullptr, LK, 90);
  // S13: s2 = s + sa @ Wtp + btp (in-place into x2 rows 64..243)
  hipLaunchKernelGGL(cvt_wt, dim3(768 / 32, 768 / 32), dim3(256), 0, stream,
                     Wtp, WTS, DD, DD, 0);
  hipLaunchKernelGGL((gemm_mfma<0>), dim3(768 / 128, (BB * LK) / 128), dim3(256), 0, stream,
                     (const void*)SAp, WTS, btp, wsf + OFF_X2,
                     wsf + OFF_X2, DD, (unsigned short*)nullptr, 1, DD,
                     BB * LK, DD, DD, LK, (long long)244 * DD, NT, 0);
  // S14: h2 = LN(x2) -> bf16
  hipLaunchKernelGGL((ln_kernel<1>), dim3(BB * 244), dim3(256), 0, stream,
                     wsf + OFF_X2, (float*)nullptr, H2p, g2, b2, BB * 244, 0LL, 0);
  // S15: mid = gelu(h2 @ W1 + b1m) -> bf16
  hipLaunchKernelGGL(cvt_wt, dim3(3072 / 32, 768 / 32), dim3(256), 0, stream,
                     W1, WTS2, DD, 4 * DD, 0);
  hipLaunchKernelGGL((gemm_mfma<0>), dim3(3072 / 128, (BB * 244) / 128), dim3(256), 0, stream,
                     (const void*)H2p, WTS2, b1m, (const float*)nullptr,
                     (float*)nullptr, 1, MIDp, 4 * DD, 0,
                     BB * 244, 4 * DD, DD, BB * 244, 0LL, 0, 1);
  // S16: x_out = x2 + mid @ W2 + b2m -> f32 d_out
  hipLaunchKernelGGL(cvt_wt, dim3(768 / 32, 3072 / 32), dim3(256), 0, stream,
                     W2, WTS2, 4 * DD, DD, 0);
  hipLaunchKernelGGL((gemm_mfma<0>), dim3(768 / 128, (BB * 244) / 128), dim3(256), 0, stream,
                     (const void*)MIDp, WTS2, b2m, wsf + OFF_X2,
                     out + O_X, DD, (unsigned short*)nullptr, 1, DD,
                     BB * 244, DD, 4 * DD, BB * 244, 0LL, 0, 0);
}

// Round 8
// 1088.200 us; speedup vs baseline: 4.8279x; 1.2892x over previous
//
#include <hip/hip_runtime.h>
#include <hip/hip_bf16.h>

// Problem constants
#define BB 32
#define NT 64
#define NS 256
#define NN 320
#define NPS 256
#define DD 768
#define HH 12
#define DHD 64
#define LK 180
#define NREM 76

// ws layout (float-element offsets). Peak 30,605,760 f = 122.4 MB.
#define OFF_HF    0LL          // f32 [10240][768]  S1-S2c
#define OFF_KF    7864320LL    // f32 [10240][768]  S2a-S3
#define OFF_QTF   15728640LL   // f32 [2048][768]   S2b-S3A
#define OFF_QV    17301504LL   // bf16[10240][1536] S2c-S3 (q cols 0..767, v 768..1535)
#define OFF_WQVT  25165824LL   // bf16[1536][768]   S0-S2c
#define OFF_XA    0LL          // bf16[10240][768]  S3-S4 (HF dead)
#define OFF_X1    12000000LL   // f32 [10240][768]  S4-S7
#define OFF_X2    0LL          // f32 [7808][768]   S7-S16
#define OFF_SN    6000000LL    // bf16[5760][768]   S8-S9
#define OFF_QT2   20000000LL   // bf16[5760][768]   S9-S12
#define OFF_KT    22300000LL   // bf16[8192][768]   S10-S12
#define OFF_VT    25500000LL   // bf16[8192][768]   S11-S12
#define OFF_SA    6000000LL    // bf16[5760][768]   S12-S13 (SN dead)
#define OFF_H2    12000000LL   // bf16[7808][768]   S14-S15 (X1 dead)
#define OFF_MIDB  15000000LL   // bf16[7808][3072]  S15-S16
#define OFF_WTS   29000000LL   // bf16[768][768] serial small-W slot
#define OFF_WTS2  29300000LL   // bf16[3072][768] W1t/W2t slot
#define OFF_ATP   30500000LL   // f32 384*256
#define OFF_TOPK  30600000LL   // int 5760

// d_out (f32) offsets: (x, git, keep, removed, attn)
#define O_X    0LL
#define O_GIT  5996544LL
#define O_KEEP 5998592LL
#define O_REM  6004352LL
#define O_ATTN 6006784LL

typedef __attribute__((ext_vector_type(8))) short short8v;
typedef __attribute__((ext_vector_type(4))) float f32x4;

__device__ __forceinline__ float bf2f(unsigned short u) {
  return __uint_as_float((unsigned)u << 16);
}
__device__ __forceinline__ unsigned short f2bfu(float f) {
  __hip_bfloat16 h = __float2bfloat16(f);
  return *reinterpret_cast<unsigned short*>(&h);
}

// ---------------- LayerNorm. OMODE: 0=f32 out, 1=bf16 out -------------------
template<int OMODE>
__global__ __launch_bounds__(256) void ln_kernel(
    const float* __restrict__ in, float* __restrict__ outf,
    unsigned short* __restrict__ outh,
    const float* __restrict__ g, const float* __restrict__ b,
    int rpb, long long bstride, int row0)
{
  int r = blockIdx.x, t = threadIdx.x;
  long long base = (long long)(r / rpb) * bstride + (long long)(r % rpb + row0) * DD;
  float v0 = in[base + t], v1 = in[base + 256 + t], v2 = in[base + 512 + t];
  __shared__ float red[256];
  red[t] = v0 + v1 + v2;
  __syncthreads();
  #pragma unroll
  for (int off = 128; off > 0; off >>= 1) { if (t < off) red[t] += red[t + off]; __syncthreads(); }
  float mean = red[0] * (1.f / 768.f);
  __syncthreads();
  float d0 = v0 - mean, d1 = v1 - mean, d2 = v2 - mean;
  red[t] = d0 * d0 + d1 * d1 + d2 * d2;
  __syncthreads();
  #pragma unroll
  for (int off = 128; off > 0; off >>= 1) { if (t < off) red[t] += red[t + off]; __syncthreads(); }
  float rstd = rsqrtf(red[0] * (1.f / 768.f) + 1e-5f);
  long long ob = (long long)r * DD;
  float o0 = d0 * rstd * g[t]       + b[t];
  float o1 = d1 * rstd * g[256 + t] + b[256 + t];
  float o2 = d2 * rstd * g[512 + t] + b[512 + t];
  if (OMODE == 0) {
    outf[ob + t] = o0; outf[ob + 256 + t] = o1; outf[ob + 512 + t] = o2;
  } else {
    outh[ob + t] = f2bfu(o0); outh[ob + 256 + t] = f2bfu(o1); outh[ob + 512 + t] = f2bfu(o2);
  }
}

// ------ Transpose+convert: W f32 [K][Nfull] cols [n0off..) -> bf16 [N][K] ---
__global__ __launch_bounds__(256) void cvt_wt(
    const float* __restrict__ W, unsigned short* __restrict__ Th,
    int K, int Nfull, int n0off)
{
  __shared__ float tile[32][33];
  int n0 = blockIdx.x * 32, k0 = blockIdx.y * 32;
  int tx = threadIdx.x & 31, ty4 = (threadIdx.x >> 5) * 4;
  #pragma unroll
  for (int i = 0; i < 4; ++i)
    tile[ty4 + i][tx] = W[(long long)(k0 + ty4 + i) * Nfull + n0off + n0 + tx];
  __syncthreads();
  #pragma unroll
  for (int i = 0; i < 4; ++i)
    Th[(long long)(n0 + ty4 + i) * K + k0 + tx] = f2bfu(tile[tx][ty4 + i]);
}

// -------- f32 vector GEMM (order-critical): C = A @ W -----------------------
// A-row map: global row r -> A offset (r/a_rpb)*a_bstride + (r%a_rpb)*K.
__global__ __launch_bounds__(256) void gemm_k(
    const float* __restrict__ A, int a_rpb, long long a_bstride,
    const float* __restrict__ W, int wst,
    float* __restrict__ Cf, int c_ld, int M, int K)
{
  __shared__ float As[16][132];
  __shared__ float Ws[16][132];
  int t = threadIdx.x;
  long long bm = (long long)blockIdx.y * 128;
  long long bn = (long long)blockIdx.x * 128;
  float acc[8][8] = {};
  int wid = t >> 6, lane = t & 63;
  int tm = ((wid >> 1) << 6) + ((lane >> 3) << 3);
  int tn = ((wid & 1) << 6) + ((lane & 7) << 3);
  long long abase[2];
  #pragma unroll
  for (int l = 0; l < 2; ++l) {
    int idx = (t + (l << 8)) << 2;
    long long r = bm + (idx >> 4);
    abase[l] = (r / a_rpb) * a_bstride + (r % a_rpb) * (long long)K;
  }
  for (int k0 = 0; k0 < K; k0 += 16) {
    #pragma unroll
    for (int l = 0; l < 2; ++l) {
      int idx = (t + (l << 8)) << 2;
      int m = idx >> 4, kk = idx & 15;
      const float4 a4 = *reinterpret_cast<const float4*>(A + abase[l] + k0 + kk);
      As[kk + 0][m] = a4.x; As[kk + 1][m] = a4.y; As[kk + 2][m] = a4.z; As[kk + 3][m] = a4.w;
      int kw = idx >> 7, n = idx & 127;
      *reinterpret_cast<float4*>(&Ws[kw][n]) =
          *reinterpret_cast<const float4*>(W + (long long)(k0 + kw) * wst + bn + n);
    }
    __syncthreads();
    #pragma unroll
    for (int kk = 0; kk < 16; ++kk) {
      float a[8], w[8];
      *reinterpret_cast<float4*>(a)     = *reinterpret_cast<const float4*>(&As[kk][tm]);
      *reinterpret_cast<float4*>(a + 4) = *reinterpret_cast<const float4*>(&As[kk][tm + 4]);
      *reinterpret_cast<float4*>(w)     = *reinterpret_cast<const float4*>(&Ws[kk][tn]);
      *reinterpret_cast<float4*>(w + 4) = *reinterpret_cast<const float4*>(&Ws[kk][tn + 4]);
      #pragma unroll
      for (int i = 0; i < 8; ++i)
        #pragma unroll
        for (int j = 0; j < 8; ++j)
          acc[i][j] = fmaf(a[i], w[j], acc[i][j]);
    }
    __syncthreads();
  }
  #pragma unroll
  for (int i = 0; i < 8; ++i) {
    long long crow = (bm + tm + i) * c_ld;
    #pragma unroll
    for (int j = 0; j < 8; ++j)
      Cf[crow + bn + tn + j] = acc[i][j];
  }
}

// -------- MFMA GEMM: C = act(A @ Bt^T + bias) + resid -----------------------
template<int AF32>
__global__ __launch_bounds__(256) void gemm_mfma(
    const void* __restrict__ A, const unsigned short* __restrict__ Bt,
    const float* __restrict__ bias, const float* __restrict__ resid,
    float* __restrict__ Cf, int ldf,
    unsigned short* __restrict__ Cb, int ldb, int colsplit,
    int M, int N, int K,
    int c_rpb, long long c_bstride, int c_row0, int act)
{
  __shared__ unsigned short As[128 * 40], Bs[128 * 40];
  const unsigned short* Ab = (const unsigned short*)A;
  const float* Af = (const float*)A;
  int t = threadIdx.x;
  long long bm = (long long)blockIdx.y * 128;
  long long bn = (long long)blockIdx.x * 128;
  int wid = t >> 6, lane = t & 63;
  int wr = (wid >> 1) << 6, wc = (wid & 1) << 6;
  f32x4 acc[4][4];
  #pragma unroll
  for (int m = 0; m < 4; ++m)
    #pragma unroll
    for (int n = 0; n < 4; ++n) acc[m][n] = (f32x4){0.f, 0.f, 0.f, 0.f};
  for (int k0 = 0; k0 < K; k0 += 32) {
    #pragma unroll
    for (int l = 0; l < 2; ++l) {
      int e = (t + (l << 8)) << 3;
      int row = e >> 5, kk = e & 31;
      int ls = row * 40 + kk;
      if (AF32) {
        const float4 f0 = *reinterpret_cast<const float4*>(&Af[(bm + row) * K + k0 + kk]);
        const float4 f1 = *reinterpret_cast<const float4*>(&Af[(bm + row) * K + k0 + kk + 4]);
        ushort4 u0, u1;
        u0.x = f2bfu(f0.x); u0.y = f2bfu(f0.y); u0.z = f2bfu(f0.z); u0.w = f2bfu(f0.w);
        u1.x = f2bfu(f1.x); u1.y = f2bfu(f1.y); u1.z = f2bfu(f1.z); u1.w = f2bfu(f1.w);
        *reinterpret_cast<ushort4*>(&As[ls])     = u0;
        *reinterpret_cast<ushort4*>(&As[ls + 4]) = u1;
      } else {
        *reinterpret_cast<int4*>(&As[ls]) = *reinterpret_cast<const int4*>(&Ab[(bm + row) * K + k0 + kk]);
      }
      *reinterpret_cast<int4*>(&Bs[ls]) = *reinterpret_cast<const int4*>(&Bt[(bn + row) * K + k0 + kk]);
    }
    __syncthreads();
    int ra = (wr + (lane & 15)) * 40 + ((lane >> 4) << 3);
    int rb = (wc + (lane & 15)) * 40 + ((lane >> 4) << 3);
    short8v a[4], b[4];
    #pragma unroll
    for (int m = 0; m < 4; ++m) {
      a[m] = *reinterpret_cast<const short8v*>(&As[ra + m * 16 * 40]);
      b[m] = *reinterpret_cast<const short8v*>(&Bs[rb + m * 16 * 40]);
    }
    #pragma unroll
    for (int m = 0; m < 4; ++m)
      #pragma unroll
      for (int n = 0; n < 4; ++n)
        acc[m][n] = __builtin_amdgcn_mfma_f32_16x16x32_bf16(a[m], b[n], acc[m][n], 0, 0, 0);
    __syncthreads();
  }
  int ro = (lane >> 4) << 2, co = lane & 15;
  #pragma unroll
  for (int m = 0; m < 4; ++m) {
    #pragma unroll
    for (int j = 0; j < 4; ++j) {
      long long r = bm + wr + m * 16 + ro + j;
      long long base = (r / c_rpb) * c_bstride + (long long)((int)(r % c_rpb) + c_row0) * ldf;
      #pragma unroll
      for (int n = 0; n < 4; ++n) {
        long long c = bn + wc + n * 16 + co;
        float v = acc[m][n][j];
        if (bias) v += bias[c];
        if (act) v = 0.5f * v * (1.f + erff(v * 0.70710678118654752f));
        if (resid) v += resid[base + c];
        if (c < colsplit) Cf[base + c] = v;
        else Cb[r * ldb + (c - colsplit)] = f2bfu(v);
      }
    }
  }
}

// ======== MFMA flash attention (value path): swapped QK^T, pi-permuted PV ===
// Per block: NW waves, each wave owns 16 q-rows. Full-row softmax.
// QK: S^T = mfma(K_frag, q_frag): lane holds P[q=lane&15][kcol=16*mt+4*(lane>>4)+j]
// PV: A-frag packed from P regs (slot g*8+i <-> kcol 16*(i>>2)+4*g+(i&3));
//     V staged into LDS with the same permutation -> no P round-trip.
template<int NKV, int NW, int PROBS, int KF32>
__global__ __launch_bounds__(NW * 64) void attn_mfma(
    const unsigned short* __restrict__ q, int q_rs, int q_bs, int q_off,
    const void* __restrict__ kv, int k_rs,
    const unsigned short* __restrict__ v, int v_rs,
    unsigned short* __restrict__ xab, int xa_rs, int xa_bs, int xa_off,
    float* __restrict__ probs, int NQtot)
{
  constexpr int KST = 68;
  constexpr int VST = NKV + 4;
  constexpr int NT_K = NKV / 16;
  constexpr int NTH = NW * 64;
  __shared__ unsigned short ksh[NKV * KST];
  __shared__ unsigned short qsh[NW * 16 * KST];
  __shared__ unsigned short vsh[64 * VST];
  __shared__ float ldsT[PROBS ? NW * 16 * 17 : 1];
  int bh = blockIdx.x, b = bh / HH, h = bh % HH;
  int rb = blockIdx.y * (NW * 16);
  int t = threadIdx.x;
  const float* kf = (const float*)kv;
  const unsigned short* ku = (const unsigned short*)kv;
  for (int i = t; i < NKV * 64; i += NTH) {
    int kr = i >> 6, d = i & 63;
    long long gi = (long long)(b * NKV + kr);
    ksh[kr * KST + d] = KF32 ? f2bfu(kf[gi * k_rs + h * DHD + d])
                             : ku[gi * k_rs + h * DHD + d];
    int kp = (kr & ~31) | (((kr >> 2) & 3) << 3) | (((kr >> 4) & 1) << 2) | (kr & 3);
    vsh[d * VST + kp] = v[gi * v_rs + h * DHD + d];
  }
  for (int i = t; i < NW * 16 * 64; i += NTH) {
    int qr = i >> 6, d = i & 63;
    int qg = rb + qr;
    qsh[qr * KST + d] = (qg < NQtot)
      ? q[(long long)(b * q_bs + q_off + qg) * q_rs + h * DHD + d] : (unsigned short)0;
  }
  __syncthreads();
  int wid = t >> 6, lane = t & 63;
  int l15 = lane & 15, lg = lane >> 4;
  // ---- QK^T swapped ----
  short8v bq[2];
  #pragma unroll
  for (int ks = 0; ks < 2; ++ks)
    bq[ks] = *reinterpret_cast<const short8v*>(&qsh[(wid * 16 + l15) * KST + ks * 32 + lg * 8]);
  f32x4 s[NT_K];
  #pragma unroll
  for (int mt = 0; mt < NT_K; ++mt) s[mt] = (f32x4){0.f, 0.f, 0.f, 0.f};
  #pragma unroll
  for (int mt = 0; mt < NT_K; ++mt)
    #pragma unroll
    for (int ks = 0; ks < 2; ++ks) {
      short8v ka = *reinterpret_cast<const short8v*>(&ksh[(mt * 16 + l15) * KST + ks * 32 + lg * 8]);
      s[mt] = __builtin_amdgcn_mfma_f32_16x16x32_bf16(ka, bq[ks], s[mt], 0, 0, 0);
    }
  // ---- softmax (per q-row = l15; reduce over {lane, lane^16, lane^32, lane^48}) ----
  float m = -3.4e38f;
  #pragma unroll
  for (int mt = 0; mt < NT_K; ++mt)
    #pragma unroll
    for (int j = 0; j < 4; ++j) { s[mt][j] *= 0.125f; m = fmaxf(m, s[mt][j]); }
  m = fmaxf(m, __shfl_xor(m, 16)); m = fmaxf(m, __shfl_xor(m, 32));
  float ss = 0.f;
  #pragma unroll
  for (int mt = 0; mt < NT_K; ++mt)
    #pragma unroll
    for (int j = 0; j < 4; ++j) { s[mt][j] = __expf(s[mt][j] - m); ss += s[mt][j]; }
  ss += __shfl_xor(ss, 16); ss += __shfl_xor(ss, 32);
  float inv = 1.f / ss;
  #pragma unroll
  for (int mt = 0; mt < NT_K; ++mt)
    #pragma unroll
    for (int j = 0; j < 4; ++j) s[mt][j] *= inv;
  // ---- probs f32 out (coalesced via per-wave LDS transpose tile) ----
  if (PROBS) {
    float* lT = &ldsT[wid * 16 * 17];
    #pragma unroll
    for (int mt = 0; mt < NT_K; ++mt) {
      #pragma unroll
      for (int j = 0; j < 4; ++j) lT[l15 * 17 + lg * 4 + j] = s[mt][j];
      #pragma unroll
      for (int m4 = 0; m4 < 4; ++m4) {
        int qr = wid * 16 + m4 * 4 + lg;
        int qg = rb + qr;
        if (qg < NQtot)
          probs[((long long)(bh * q_bs + q_off + qg)) * NKV + mt * 16 + l15] =
              lT[(m4 * 4 + lg) * 17 + l15];
      }
    }
  }
  // ---- PV ----
  f32x4 o[4];
  #pragma unroll
  for (int nt = 0; nt < 4; ++nt) o[nt] = (f32x4){0.f, 0.f, 0.f, 0.f};
  #pragma unroll
  for (int c = 0; c < NKV / 32; ++c) {
    short8v a8;
    #pragma unroll
    for (int j = 0; j < 4; ++j) {
      a8[j]     = (short)f2bfu(s[2 * c][j]);
      a8[4 + j] = (short)f2bfu(s[2 * c + 1][j]);
    }
    #pragma unroll
    for (int nt = 0; nt < 4; ++nt) {
      short8v bv = *reinterpret_cast<const short8v*>(&vsh[(nt * 16 + l15) * VST + c * 32 + lg * 8]);
      o[nt] = __builtin_amdgcn_mfma_f32_16x16x32_bf16(a8, bv, o[nt], 0, 0, 0);
    }
  }
  #pragma unroll
  for (int nt = 0; nt < 4; ++nt)
    #pragma unroll
    for (int j = 0; j < 4; ++j) {
      int qg = rb + wid * 16 + lg * 4 + j;
      if (qg < NQtot)
        xab[(long long)(b * xa_bs + xa_off + qg) * xa_rs + h * DHD + nt * 16 + l15] =
            f2bfu(o[nt][j]);
    }
}

// ---- f32 attention for template rows (q<64): exact round-7 numerics --------
__global__ __launch_bounds__(1024) void attn_tmpl(
    const float* __restrict__ qt, const float* __restrict__ kf,
    const unsigned short* __restrict__ vb,
    unsigned short* __restrict__ xab, float* __restrict__ probs,
    float* __restrict__ atp)
{
  constexpr int VST = NN + 4;
  __shared__ float ksh[NN * 65];
  __shared__ unsigned short vsh[64 * VST];
  __shared__ float pss[16][NN];
  __shared__ float qsh[16][64];
  int bh = blockIdx.x, b = bh / HH, h = bh % HH;
  int t = threadIdx.x;
  for (int i = t; i < NN * 64; i += 1024) {
    int rr = i >> 6, d = i & 63;
    long long gi = (long long)(b * NN + rr);
    ksh[rr * 65 + d] = kf[gi * 768 + h * DHD + d];
    vsh[d * VST + rr] = vb[gi * 1536 + h * DHD + d];
  }
  __syncthreads();
  int wid = t >> 6, lane = t & 63;
  float at[4] = {};
  for (int q = wid; q < NT; q += 16) {
    qsh[wid][lane] = qt[(long long)(b * NT + q) * 768 + h * DHD + lane];
    float s[5];
    #pragma unroll
    for (int r = 0; r < 5; ++r) s[r] = 0.f;
    const float* kp = ksh + lane * 65;
    #pragma unroll 16
    for (int d = 0; d < 64; ++d) {
      float qd = qsh[wid][d];
      #pragma unroll
      for (int r = 0; r < 5; ++r)
        s[r] = fmaf(qd, kp[(r << 6) * 65 + d], s[r]);
    }
    float m = -3.4e38f;
    #pragma unroll
    for (int r = 0; r < 5; ++r) { s[r] *= 0.125f; m = fmaxf(m, s[r]); }
    #pragma unroll
    for (int off = 32; off > 0; off >>= 1) m = fmaxf(m, __shfl_xor(m, off));
    float ss = 0.f;
    #pragma unroll
    for (int r = 0; r < 5; ++r) { s[r] = __expf(s[r] - m); ss += s[r]; }
    #pragma unroll
    for (int off = 32; off > 0; off >>= 1) ss += __shfl_xor(ss, off);
    float inv = 1.f / ss;
    long long pb = ((long long)(bh * NN) + q) * NN;
    #pragma unroll
    for (int r = 0; r < 5; ++r) {
      float p = s[r] * inv;
      s[r] = p;
      pss[wid][lane + (r << 6)] = p;
      probs[pb + lane + (r << 6)] = p;
    }
    #pragma unroll
    for (int r = 1; r < 5; ++r) at[r - 1] += s[r];
    float acc = 0.f;
    const unsigned short* vp = vsh + lane * VST;
    #pragma unroll 8
    for (int j = 0; j < NN; j += 4) {
      float4 p4 = *reinterpret_cast<const float4*>(&pss[wid][j]);
      ushort4 v4 = *reinterpret_cast<const ushort4*>(&vp[j]);
      acc = fmaf(p4.x, bf2f(v4.x), acc);
      acc = fmaf(p4.y, bf2f(v4.y), acc);
      acc = fmaf(p4.z, bf2f(v4.z), acc);
      acc = fmaf(p4.w, bf2f(v4.w), acc);
    }
    xab[(long long)(b * NN + q) * 768 + h * DHD + lane] = f2bfu(acc);
  }
  #pragma unroll
  for (int r = 1; r < 5; ++r) pss[wid][lane + ((r - 1) << 6)] = at[r - 1];
  __syncthreads();
  if (t < 256) {
    float v = 0.f;
    #pragma unroll
    for (int w = 0; w < 16; ++w) v += pss[w][t];
    atp[(long long)bh * 256 + t] = v;
  }
}

// ---- Per-batch argsort(-attn_t), stable; emit keep/removed -----------------
__global__ __launch_bounds__(256) void sort_kernel(
    const float* __restrict__ atp, const int* __restrict__ gis,
    float* __restrict__ keep_out, float* __restrict__ rem_out,
    int* __restrict__ topk)
{
  int b = blockIdx.x, t = threadIdx.x;
  __shared__ float sv[256];
  __shared__ int   si[256];
  float v = 0.f;
  for (int h = 0; h < HH; ++h) v += atp[((long long)(b * HH + h) << 8) + t];
  sv[t] = v; si[t] = t;
  __syncthreads();
  for (int k = 2; k <= 256; k <<= 1) {
    for (int j = k >> 1; j > 0; j >>= 1) {
      int ixj = t ^ j;
      if (ixj > t) {
        float va = sv[t], vb2 = sv[ixj];
        int ia = si[t], ib = si[ixj];
        bool after = (va < vb2) || (va == vb2 && ia > ib);
        bool dirUp = ((t & k) == 0);
        if (after == dirUp) { sv[t] = vb2; sv[ixj] = va; si[t] = ib; si[ixj] = ia; }
      }
      __syncthreads();
    }
  }
  int o = si[t];
  if (t < LK) {
    topk[b * LK + t] = o;
    keep_out[b * LK + t] = (float)gis[(b << 8) + o];
  } else {
    rem_out[b * NREM + (t - LK)] = (float)gis[(b << 8) + o];
  }
}

__global__ __launch_bounds__(256) void gather_kernel(
    const float* __restrict__ x1, const int* __restrict__ topk, float* __restrict__ x2)
{
  int r = blockIdx.x, t = threadIdx.x;
  int b = r / 244, rr = r % 244;
  int src = (rr < NT) ? rr : (NT + topk[b * LK + (rr - NT)]);
  const float* s = x1 + (long long)(b * NN + src) * DD;
  float* d = x2 + (long long)r * DD;
  d[t] = s[t]; d[256 + t] = s[256 + t]; d[512 + t] = s[512 + t];
}

__global__ void git_kernel(const int* __restrict__ git, float* __restrict__ o)
{
  int i = blockIdx.x * 256 + threadIdx.x;
  if (i < BB * NT) o[i] = (float)git[i];
}

extern "C" void kernel_launch(void* const* d_in, const int* in_sizes, int n_in,
                              void* d_out, int out_size, void* d_ws, size_t ws_size,
                              hipStream_t stream) {
  (void)in_sizes; (void)n_in; (void)out_size; (void)ws_size;
  const float* x    = (const float*)d_in[0];
  const float* ps   = (const float*)d_in[1];
  const int*   git  = (const int*)d_in[2];
  const int*   gis  = (const int*)d_in[3];
  const float* g1   = (const float*)d_in[4];
  const float* b1   = (const float*)d_in[5];
  const float* Wqkv = (const float*)d_in[6];
  const float* Wproj= (const float*)d_in[7];
  const float* bproj= (const float*)d_in[8];
  const float* gt   = (const float*)d_in[9];
  const float* bt   = (const float*)d_in[10];
  const float* Wq   = (const float*)d_in[11];
  const float* Wk   = (const float*)d_in[12];
  const float* Wv   = (const float*)d_in[13];
  const float* Wtp  = (const float*)d_in[14];
  const float* btp  = (const float*)d_in[15];
  const float* g2   = (const float*)d_in[16];
  const float* b2   = (const float*)d_in[17];
  const float* W1   = (const float*)d_in[18];
  const float* b1m  = (const float*)d_in[19];
  const float* W2   = (const float*)d_in[20];
  const float* b2m  = (const float*)d_in[21];
  float* wsf = (float*)d_ws;
  float* out = (float*)d_out;
  unsigned short* WQVT = (unsigned short*)(wsf + OFF_WQVT);
  unsigned short* QVp  = (unsigned short*)(wsf + OFF_QV);
  unsigned short* XAp  = (unsigned short*)(wsf + OFF_XA);
  unsigned short* WTS  = (unsigned short*)(wsf + OFF_WTS);
  unsigned short* WTS2 = (unsigned short*)(wsf + OFF_WTS2);
  unsigned short* SNp  = (unsigned short*)(wsf + OFF_SN);
  unsigned short* QT2p = (unsigned short*)(wsf + OFF_QT2);
  unsigned short* KTp  = (unsigned short*)(wsf + OFF_KT);
  unsigned short* VTp  = (unsigned short*)(wsf + OFF_VT);
  unsigned short* SAp  = (unsigned short*)(wsf + OFF_SA);
  unsigned short* H2p  = (unsigned short*)(wsf + OFF_H2);
  unsigned short* MIDp = (unsigned short*)(wsf + OFF_MIDB);

  // S0: Wqkv q-part and v-part -> transposed bf16 [1536][768]
  hipLaunchKernelGGL(cvt_wt, dim3(24, 24), dim3(256), 0, stream,
                     Wqkv, WQVT, DD, 3 * DD, 0);
  hipLaunchKernelGGL(cvt_wt, dim3(24, 24), dim3(256), 0, stream,
                     Wqkv, WQVT + 768 * 768, DD, 3 * DD, 1536);
  // S1: h = LN(x) -> f32
  hipLaunchKernelGGL((ln_kernel<0>), dim3(BB * NN), dim3(256), 0, stream,
                     x, wsf + OFF_HF, (unsigned short*)nullptr, g1, b1, BB * NN, 0LL, 0);
  // S2a: k = h @ Wqkv[:,768:1536]  (f32, exact)
  hipLaunchKernelGGL(gemm_k, dim3(6, 80), dim3(256), 0, stream,
                     wsf + OFF_HF, BB * NN, 0LL, Wqkv + 768, 3 * DD,
                     wsf + OFF_KF, DD, BB * NN, DD);
  // S2b: q_template = h[rows b*320+0..63] @ Wqkv[:,0:768]  (f32, exact)
  hipLaunchKernelGGL(gemm_k, dim3(6, 16), dim3(256), 0, stream,
                     wsf + OFF_HF, NT, (long long)NN * DD, Wqkv, 3 * DD,
                     wsf + OFF_QTF, DD, BB * NT, DD);
  // S2c: [q|v] = h @ [Wq-part|Wv-part]  (MFMA bf16)
  hipLaunchKernelGGL((gemm_mfma<1>), dim3(12, 80), dim3(256), 0, stream,
                     (const void*)(wsf + OFF_HF), WQVT,
                     (const float*)nullptr, (const float*)nullptr,
                     (float*)nullptr, 1, QVp, 1536, 0,
                     BB * NN, 1536, DD, BB * NN, 0LL, 0, 0);
  // S3B: MFMA attention rows 64..319 -> probs, xa
  hipLaunchKernelGGL((attn_mfma<NN, 8, 1, 1>), dim3(BB * HH, 2), dim3(512), 0, stream,
                     QVp, 1536, NN, NT,
                     (const void*)(wsf + OFF_KF), DD,
                     QVp + 768, 1536,
                     XAp, DD, NN, NT,
                     out + O_ATTN, 256);
  // S3A: f32 attention rows <64 -> probs, xa, attn_t (bitwise = round 7)
  hipLaunchKernelGGL(attn_tmpl, dim3(BB * HH), dim3(1024), 0, stream,
                     wsf + OFF_QTF, wsf + OFF_KF, QVp + 768,
                     XAp, out + O_ATTN, wsf + OFF_ATP);
  // S4: x1 = x + xa @ Wproj + bproj
  hipLaunchKernelGGL(cvt_wt, dim3(24, 24), dim3(256), 0, stream, Wproj, WTS, DD, DD, 0);
  hipLaunchKernelGGL((gemm_mfma<0>), dim3(6, 80), dim3(256), 0, stream,
                     (const void*)XAp, WTS, bproj, x,
                     wsf + OFF_X1, DD, (unsigned short*)nullptr, 1, DD,
                     BB * NN, DD, DD, BB * NN, 0LL, 0, 0);
  // S5/S6/S7
  hipLaunchKernelGGL(sort_kernel, dim3(BB), dim3(256), 0, stream,
                     wsf + OFF_ATP, gis, out + O_KEEP, out + O_REM,
                     (int*)(wsf + OFF_TOPK));
  hipLaunchKernelGGL(git_kernel, dim3((BB * NT + 255) / 256), dim3(256), 0, stream,
                     git, out + O_GIT);
  hipLaunchKernelGGL(gather_kernel, dim3(BB * 244), dim3(256), 0, stream,
                     wsf + OFF_X1, (const int*)(wsf + OFF_TOPK), wsf + OFF_X2);
  // S8: sn = LN(s) -> bf16
  hipLaunchKernelGGL((ln_kernel<1>), dim3(BB * LK), dim3(256), 0, stream,
                     wsf + OFF_X2, (float*)nullptr, SNp, gt, bt, LK, (long long)244 * DD, NT);
  // S9: qT = sn @ Wq -> bf16
  hipLaunchKernelGGL(cvt_wt, dim3(24, 24), dim3(256), 0, stream, Wq, WTS, DD, DD, 0);
  hipLaunchKernelGGL((gemm_mfma<0>), dim3(6, 45), dim3(256), 0, stream,
                     (const void*)SNp, WTS, (const float*)nullptr, (const float*)nullptr,
                     (float*)nullptr, 1, QT2p, DD, 0,
                     BB * LK, DD, DD, BB * LK, 0LL, 0, 0);
  // S10: kT = ps @ Wk -> bf16 (f32 A staged)
  hipLaunchKernelGGL(cvt_wt, dim3(24, 24), dim3(256), 0, stream, Wk, WTS, DD, DD, 0);
  hipLaunchKernelGGL((gemm_mfma<1>), dim3(6, 64), dim3(256), 0, stream,
                     (const void*)ps, WTS, (const float*)nullptr, (const float*)nullptr,
                     (float*)nullptr, 1, KTp, DD, 0,
                     BB * NPS, DD, DD, BB * NPS, 0LL, 0, 0);
  // S11: vT = ps @ Wv -> bf16
  hipLaunchKernelGGL(cvt_wt, dim3(24, 24), dim3(256), 0, stream, Wv, WTS, DD, DD, 0);
  hipLaunchKernelGGL((gemm_mfma<1>), dim3(6, 64), dim3(256), 0, stream,
                     (const void*)ps, WTS, (const float*)nullptr, (const float*)nullptr,
                     (float*)nullptr, 1, VTp, DD, 0,
                     BB * NPS, DD, DD, BB * NPS, 0LL, 0, 0);
  // S12: stage-2 attention (MFMA) -> sa bf16
  hipLaunchKernelGGL((attn_mfma<NPS, 8, 0, 0>), dim3(BB * HH, 2), dim3(512), 0, stream,
                     QT2p, DD, LK, 0,
                     (const void*)KTp, DD,
                     VTp, DD,
                     SAp, DD, LK, 0,
                     (float*)nullptr, LK);
  // S13: s2 = s + sa @ Wtp + btp (into x2 rows 64..243)
  hipLaunchKernelGGL(cvt_wt, dim3(24, 24), dim3(256), 0, stream, Wtp, WTS, DD, DD, 0);
  hipLaunchKernelGGL((gemm_mfma<0>), dim3(6, 45), dim3(256), 0, stream,
                     (const void*)SAp, WTS, btp, wsf + OFF_X2,
                     wsf + OFF_X2, DD, (unsigned short*)nullptr, 1, DD,
                     BB * LK, DD, DD, LK, (long long)244 * DD, NT, 0);
  // S14: h2 = LN(x2) -> bf16
  hipLaunchKernelGGL((ln_kernel<1>), dim3(BB * 244), dim3(256), 0, stream,
                     wsf + OFF_X2, (float*)nullptr, H2p, g2, b2, BB * 244, 0LL, 0);
  // S15: mid = gelu(h2 @ W1 + b1m) -> bf16
  hipLaunchKernelGGL(cvt_wt, dim3(96, 24), dim3(256), 0, stream, W1, WTS2, DD, 4 * DD, 0);
  hipLaunchKernelGGL((gemm_mfma<0>), dim3(24, 61), dim3(256), 0, stream,
                     (const void*)H2p, WTS2, b1m, (const float*)nullptr,
                     (float*)nullptr, 1, MIDp, 4 * DD, 0,
                     BB * 244, 4 * DD, DD, BB * 244, 0LL, 0, 1);
  // S16: x_out = x2 + mid @ W2 + b2m -> f32 d_out
  hipLaunchKernelGGL(cvt_wt, dim3(24, 96), dim3(256), 0, stream, W2, WTS2, 4 * DD, DD, 0);
  hipLaunchKernelGGL((gemm_mfma<0>), dim3(6, 61), dim3(256), 0, stream,
                     (const void*)MIDp, WTS2, b2m, wsf + OFF_X2,
                     out + O_X, DD, (unsigned short*)nullptr, 1, DD,
                     BB * 244, DD, 4 * DD, BB * 244, 0LL, 0, 0);
}

// Round 10
// 1078.320 us; speedup vs baseline: 4.8721x; 1.0092x over previous
//
#include <hip/hip_runtime.h>
#include <hip/hip_bf16.h>

// Problem constants
#define BB 32
#define NT 64
#define NS 256
#define NN 320
#define NPS 256
#define DD 768
#define HH 12
#define DHD 64
#define LK 180
#define NREM 76

// ws layout (float-element offsets). Peak 32.18M f = 128.7MB (ws >= ~158MB, r1).
#define OFF_HF    0LL          // f32 [10240][768]  S1-S2c
#define OFF_KF    7864320LL    // f32 [10240][768]  S2a-S3
#define OFF_QTF   15728640LL   // f32 [2048][768]   S2b-S3A
#define OFF_QV    17301504LL   // bf16[10240][1536] S2c-S3
#define OFF_WQVT  25165824LL   // bf16 2x[768][768] S0-S2c
#define OFF_XA    0LL          // bf16[10240][768]  S3-S4 (HF dead)
#define OFF_X1    12000000LL   // f32 [10240][768]  S4-S7
#define OFF_X2    0LL          // f32 [7808][768]   S7-S16
#define OFF_SN    6000000LL    // bf16[5760][768]   S8-S9
#define OFF_QT2   20000000LL   // bf16[5760][768]   S9-S12
#define OFF_KT    22300000LL   // bf16[8192][768]   S10-S12
#define OFF_VT    25500000LL   // bf16[8192][768]   S11-S12
#define OFF_SA    6000000LL    // bf16[5760][768]   S12-S13 (SN dead)
#define OFF_H2    12000000LL   // bf16[7808][768]   S14-S15 (X1 dead)
#define OFF_MIDB  15000000LL   // bf16[7808][3072]  S15-S16
#define OFF_WTS2  29300000LL   // bf16 W1t/W2t serial slot (ends 30,479,648)
#define OFF_ATP   30500000LL   // f32 384*256
#define OFF_TOPK  30600000LL   // int 5760
#define OFF_WSM   30700000LL   // bf16 5x[768][768] small weights (whole launch)

// d_out (f32) offsets: (x, git, keep, removed, attn)
#define O_X    0LL
#define O_GIT  5996544LL
#define O_KEEP 5998592LL
#define O_REM  6004352LL
#define O_ATTN 6006784LL

typedef __attribute__((ext_vector_type(8))) short short8v;
typedef __attribute__((ext_vector_type(4))) float f32x4;

__device__ __forceinline__ float bf2f(unsigned short u) {
  return __uint_as_float((unsigned)u << 16);
}
__device__ __forceinline__ unsigned short f2bfu(float f) {
  __hip_bfloat16 h = __float2bfloat16(f);
  return *reinterpret_cast<unsigned short*>(&h);
}

// ---------------- LayerNorm. OMODE: 0=f32 out, 1=bf16 out -------------------
template<int OMODE>
__global__ __launch_bounds__(256) void ln_kernel(
    const float* __restrict__ in, float* __restrict__ outf,
    unsigned short* __restrict__ outh,
    const float* __restrict__ g, const float* __restrict__ b,
    int rpb, long long bstride, int row0)
{
  int r = blockIdx.x, t = threadIdx.x;
  long long base = (long long)(r / rpb) * bstride + (long long)(r % rpb + row0) * DD;
  float v0 = in[base + t], v1 = in[base + 256 + t], v2 = in[base + 512 + t];
  __shared__ float red[256];
  red[t] = v0 + v1 + v2;
  __syncthreads();
  #pragma unroll
  for (int off = 128; off > 0; off >>= 1) { if (t < off) red[t] += red[t + off]; __syncthreads(); }
  float mean = red[0] * (1.f / 768.f);
  __syncthreads();
  float d0 = v0 - mean, d1 = v1 - mean, d2 = v2 - mean;
  red[t] = d0 * d0 + d1 * d1 + d2 * d2;
  __syncthreads();
  #pragma unroll
  for (int off = 128; off > 0; off >>= 1) { if (t < off) red[t] += red[t + off]; __syncthreads(); }
  float rstd = rsqrtf(red[0] * (1.f / 768.f) + 1e-5f);
  long long ob = (long long)r * DD;
  float o0 = d0 * rstd * g[t]       + b[t];
  float o1 = d1 * rstd * g[256 + t] + b[256 + t];
  float o2 = d2 * rstd * g[512 + t] + b[512 + t];
  if (OMODE == 0) {
    outf[ob + t] = o0; outf[ob + 256 + t] = o1; outf[ob + 512 + t] = o2;
  } else {
    outh[ob + t] = f2bfu(o0); outh[ob + 256 + t] = f2bfu(o1); outh[ob + 512 + t] = f2bfu(o2);
  }
}

// ------ Transpose+convert: W f32 [K][Nfull] -> bf16 [N][K]; z-planes --------
__global__ __launch_bounds__(256) void cvt_wt(
    const float* __restrict__ W, unsigned short* __restrict__ Th,
    int K, int Nfull, int n0off, int zoff, long long zdststep)
{
  __shared__ float tile[32][33];
  int z = blockIdx.z;
  unsigned short* T = Th + (long long)z * zdststep;
  int ncol = n0off + z * zoff;
  int n0 = blockIdx.x * 32, k0 = blockIdx.y * 32;
  int tx = threadIdx.x & 31, ty4 = (threadIdx.x >> 5) * 4;
  #pragma unroll
  for (int i = 0; i < 4; ++i)
    tile[ty4 + i][tx] = W[(long long)(k0 + ty4 + i) * Nfull + ncol + n0 + tx];
  __syncthreads();
  #pragma unroll
  for (int i = 0; i < 4; ++i)
    T[(long long)(n0 + ty4 + i) * K + k0 + tx] = f2bfu(tile[tx][ty4 + i]);
}

// ------ 5 small weights [768][768] -> bf16 [768][768]^T planes --------------
__global__ __launch_bounds__(256) void cvt_w5(
    const float* __restrict__ Wa, const float* __restrict__ Wb,
    const float* __restrict__ Wc, const float* __restrict__ Wd,
    const float* __restrict__ We, unsigned short* __restrict__ Th)
{
  __shared__ float tile[32][33];
  const float* srcs[5] = {Wa, Wb, Wc, Wd, We};
  const float* W = srcs[blockIdx.z];
  unsigned short* T = Th + (long long)blockIdx.z * (768 * 768);
  int n0 = blockIdx.x * 32, k0 = blockIdx.y * 32;
  int tx = threadIdx.x & 31, ty4 = (threadIdx.x >> 5) * 4;
  #pragma unroll
  for (int i = 0; i < 4; ++i)
    tile[ty4 + i][tx] = W[(long long)(k0 + ty4 + i) * 768 + n0 + tx];
  __syncthreads();
  #pragma unroll
  for (int i = 0; i < 4; ++i)
    T[(long long)(n0 + ty4 + i) * 768 + k0 + tx] = f2bfu(tile[tx][ty4 + i]);
}

// -------- f32 vector GEMM (order-critical): 512 thr, 128x128x16 -------------
// Per-output accumulation order identical to round-8 (kk ascending).
__global__ __launch_bounds__(512) void gemm_k(
    const float* __restrict__ A, int a_rpb, long long a_bstride,
    const float* __restrict__ W, int wst,
    float* __restrict__ Cf, int c_ld, int M, int K)
{
  __shared__ float As[16][132];
  __shared__ float Ws[16][132];
  int t = threadIdx.x;
  long long bm = (long long)blockIdx.y * 128;
  long long bn = (long long)blockIdx.x * 128;
  float acc[4][8] = {};
  int wid = t >> 6, lane = t & 63;
  int tm = (wid & 3) * 32 + (lane >> 3) * 4;
  int tn = (wid >> 2) * 64 + (lane & 7) * 8;
  int idx = t << 2;
  int am = idx >> 4, ak = idx & 15;
  int wk = idx >> 7, wn2 = idx & 127;
  long long r = bm + am;
  long long abase = (r / a_rpb) * a_bstride + (r % a_rpb) * (long long)K;
  for (int k0 = 0; k0 < K; k0 += 16) {
    const float4 a4 = *reinterpret_cast<const float4*>(A + abase + k0 + ak);
    As[ak + 0][am] = a4.x; As[ak + 1][am] = a4.y;
    As[ak + 2][am] = a4.z; As[ak + 3][am] = a4.w;
    *reinterpret_cast<float4*>(&Ws[wk][wn2]) =
        *reinterpret_cast<const float4*>(W + (long long)(k0 + wk) * wst + bn + wn2);
    __syncthreads();
    #pragma unroll
    for (int kk = 0; kk < 16; ++kk) {
      float a[4], w[8];
      *reinterpret_cast<float4*>(a)     = *reinterpret_cast<const float4*>(&As[kk][tm]);
      *reinterpret_cast<float4*>(w)     = *reinterpret_cast<const float4*>(&Ws[kk][tn]);
      *reinterpret_cast<float4*>(w + 4) = *reinterpret_cast<const float4*>(&Ws[kk][tn + 4]);
      #pragma unroll
      for (int i = 0; i < 4; ++i)
        #pragma unroll
        for (int j = 0; j < 8; ++j)
          acc[i][j] = fmaf(a[i], w[j], acc[i][j]);
    }
    __syncthreads();
  }
  #pragma unroll
  for (int i = 0; i < 4; ++i) {
    long long crow = (bm + tm + i) * c_ld;
    #pragma unroll
    for (int j = 0; j < 8; ++j)
      Cf[crow + bn + tn + j] = acc[i][j];
  }
}

// -------- MFMA GEMM: C = act(A @ Bt^T + bias) + resid -----------------------
template<int AF32>
__global__ __launch_bounds__(256) void gemm_mfma(
    const void* __restrict__ A, const unsigned short* __restrict__ Bt,
    const float* __restrict__ bias, const float* __restrict__ resid,
    float* __restrict__ Cf, int ldf,
    unsigned short* __restrict__ Cb, int ldb, int colsplit,
    int M, int N, int K,
    int c_rpb, long long c_bstride, int c_row0, int act)
{
  __shared__ unsigned short As[128 * 40], Bs[128 * 40];
  const unsigned short* Ab = (const unsigned short*)A;
  const float* Af = (const float*)A;
  int t = threadIdx.x;
  long long bm = (long long)blockIdx.y * 128;
  long long bn = (long long)blockIdx.x * 128;
  int wid = t >> 6, lane = t & 63;
  int wr = (wid >> 1) << 6, wc = (wid & 1) << 6;
  f32x4 acc[4][4];
  #pragma unroll
  for (int m = 0; m < 4; ++m)
    #pragma unroll
    for (int n = 0; n < 4; ++n) acc[m][n] = (f32x4){0.f, 0.f, 0.f, 0.f};
  for (int k0 = 0; k0 < K; k0 += 32) {
    #pragma unroll
    for (int l = 0; l < 2; ++l) {
      int e = (t + (l << 8)) << 3;
      int row = e >> 5, kk = e & 31;
      int ls = row * 40 + kk;
      if (AF32) {
        const float4 f0 = *reinterpret_cast<const float4*>(&Af[(bm + row) * K + k0 + kk]);
        const float4 f1 = *reinterpret_cast<const float4*>(&Af[(bm + row) * K + k0 + kk + 4]);
        ushort4 u0, u1;
        u0.x = f2bfu(f0.x); u0.y = f2bfu(f0.y); u0.z = f2bfu(f0.z); u0.w = f2bfu(f0.w);
        u1.x = f2bfu(f1.x); u1.y = f2bfu(f1.y); u1.z = f2bfu(f1.z); u1.w = f2bfu(f1.w);
        *reinterpret_cast<ushort4*>(&As[ls])     = u0;
        *reinterpret_cast<ushort4*>(&As[ls + 4]) = u1;
      } else {
        *reinterpret_cast<int4*>(&As[ls]) = *reinterpret_cast<const int4*>(&Ab[(bm + row) * K + k0 + kk]);
      }
      *reinterpret_cast<int4*>(&Bs[ls]) = *reinterpret_cast<const int4*>(&Bt[(bn + row) * K + k0 + kk]);
    }
    __syncthreads();
    int ra = (wr + (lane & 15)) * 40 + ((lane >> 4) << 3);
    int rb = (wc + (lane & 15)) * 40 + ((lane >> 4) << 3);
    short8v a[4], b[4];
    #pragma unroll
    for (int m = 0; m < 4; ++m) {
      a[m] = *reinterpret_cast<const short8v*>(&As[ra + m * 16 * 40]);
      b[m] = *reinterpret_cast<const short8v*>(&Bs[rb + m * 16 * 40]);
    }
    #pragma unroll
    for (int m = 0; m < 4; ++m)
      #pragma unroll
      for (int n = 0; n < 4; ++n)
        acc[m][n] = __builtin_amdgcn_mfma_f32_16x16x32_bf16(a[m], b[n], acc[m][n], 0, 0, 0);
    __syncthreads();
  }
  int ro = (lane >> 4) << 2, co = lane & 15;
  #pragma unroll
  for (int m = 0; m < 4; ++m) {
    #pragma unroll
    for (int j = 0; j < 4; ++j) {
      long long r = bm + wr + m * 16 + ro + j;
      long long base = (r / c_rpb) * c_bstride + (long long)((int)(r % c_rpb) + c_row0) * ldf;
      #pragma unroll
      for (int n = 0; n < 4; ++n) {
        long long c = bn + wc + n * 16 + co;
        float v = acc[m][n][j];
        if (bias) v += bias[c];
        if (act) v = 0.5f * v * (1.f + erff(v * 0.70710678118654752f));
        if (resid) v += resid[base + c];
        if (c < colsplit) Cf[base + c] = v;
        else Cb[r * ldb + (c - colsplit)] = f2bfu(v);
      }
    }
  }
}

// ======== MFMA flash attention (value path) — round-8 exact =================
template<int NKV, int NW, int PROBS, int KF32>
__global__ __launch_bounds__(NW * 64) void attn_mfma(
    const unsigned short* __restrict__ q, int q_rs, int q_bs, int q_off,
    const void* __restrict__ kv, int k_rs,
    const unsigned short* __restrict__ v, int v_rs,
    unsigned short* __restrict__ xab, int xa_rs, int xa_bs, int xa_off,
    float* __restrict__ probs, int NQtot)
{
  constexpr int KST = 68;
  constexpr int VST = NKV + 4;
  constexpr int NT_K = NKV / 16;
  constexpr int NTH = NW * 64;
  __shared__ unsigned short ksh[NKV * KST];
  __shared__ unsigned short qsh[NW * 16 * KST];
  __shared__ unsigned short vsh[64 * VST];
  __shared__ float ldsT[PROBS ? NW * 16 * 17 : 1];
  int bh = blockIdx.x, b = bh / HH, h = bh % HH;
  int rb = blockIdx.y * (NW * 16);
  int t = threadIdx.x;
  const float* kf = (const float*)kv;
  const unsigned short* ku = (const unsigned short*)kv;
  for (int i = t; i < NKV * 64; i += NTH) {
    int kr = i >> 6, d = i & 63;
    long long gi = (long long)(b * NKV + kr);
    ksh[kr * KST + d] = KF32 ? f2bfu(kf[gi * k_rs + h * DHD + d])
                             : ku[gi * k_rs + h * DHD + d];
    int kp = (kr & ~31) | (((kr >> 2) & 3) << 3) | (((kr >> 4) & 1) << 2) | (kr & 3);
    vsh[d * VST + kp] = v[gi * v_rs + h * DHD + d];
  }
  for (int i = t; i < NW * 16 * 64; i += NTH) {
    int qr = i >> 6, d = i & 63;
    int qg = rb + qr;
    qsh[qr * KST + d] = (qg < NQtot)
      ? q[(long long)(b * q_bs + q_off + qg) * q_rs + h * DHD + d] : (unsigned short)0;
  }
  __syncthreads();
  int wid = t >> 6, lane = t & 63;
  int l15 = lane & 15, lg = lane >> 4;
  short8v bq[2];
  #pragma unroll
  for (int ks = 0; ks < 2; ++ks)
    bq[ks] = *reinterpret_cast<const short8v*>(&qsh[(wid * 16 + l15) * KST + ks * 32 + lg * 8]);
  f32x4 s[NT_K];
  #pragma unroll
  for (int mt = 0; mt < NT_K; ++mt) s[mt] = (f32x4){0.f, 0.f, 0.f, 0.f};
  #pragma unroll
  for (int mt = 0; mt < NT_K; ++mt)
    #pragma unroll
    for (int ks = 0; ks < 2; ++ks) {
      short8v ka = *reinterpret_cast<const short8v*>(&ksh[(mt * 16 + l15) * KST + ks * 32 + lg * 8]);
      s[mt] = __builtin_amdgcn_mfma_f32_16x16x32_bf16(ka, bq[ks], s[mt], 0, 0, 0);
    }
  float m = -3.4e38f;
  #pragma unroll
  for (int mt = 0; mt < NT_K; ++mt)
    #pragma unroll
    for (int j = 0; j < 4; ++j) { s[mt][j] *= 0.125f; m = fmaxf(m, s[mt][j]); }
  m = fmaxf(m, __shfl_xor(m, 16)); m = fmaxf(m, __shfl_xor(m, 32));
  float ss = 0.f;
  #pragma unroll
  for (int mt = 0; mt < NT_K; ++mt)
    #pragma unroll
    for (int j = 0; j < 4; ++j) { s[mt][j] = __expf(s[mt][j] - m); ss += s[mt][j]; }
  ss += __shfl_xor(ss, 16); ss += __shfl_xor(ss, 32);
  float inv = 1.f / ss;
  #pragma unroll
  for (int mt = 0; mt < NT_K; ++mt)
    #pragma unroll
    for (int j = 0; j < 4; ++j) s[mt][j] *= inv;
  if (PROBS) {
    float* lT = &ldsT[wid * 16 * 17];
    #pragma unroll
    for (int mt = 0; mt < NT_K; ++mt) {
      #pragma unroll
      for (int j = 0; j < 4; ++j) lT[l15 * 17 + lg * 4 + j] = s[mt][j];
      #pragma unroll
      for (int m4 = 0; m4 < 4; ++m4) {
        int qg = rb + wid * 16 + m4 * 4 + lg;
        if (qg < NQtot)
          probs[((long long)(bh * q_bs + q_off + qg)) * NKV + mt * 16 + l15] =
              lT[(m4 * 4 + lg) * 17 + l15];
      }
    }
  }
  f32x4 o[4];
  #pragma unroll
  for (int nt = 0; nt < 4; ++nt) o[nt] = (f32x4){0.f, 0.f, 0.f, 0.f};
  #pragma unroll
  for (int c = 0; c < NKV / 32; ++c) {
    short8v a8;
    #pragma unroll
    for (int j = 0; j < 4; ++j) {
      a8[j]     = (short)f2bfu(s[2 * c][j]);
      a8[4 + j] = (short)f2bfu(s[2 * c + 1][j]);
    }
    #pragma unroll
    for (int nt = 0; nt < 4; ++nt) {
      short8v bv = *reinterpret_cast<const short8v*>(&vsh[(nt * 16 + l15) * VST + c * 32 + lg * 8]);
      o[nt] = __builtin_amdgcn_mfma_f32_16x16x32_bf16(a8, bv, o[nt], 0, 0, 0);
    }
  }
  #pragma unroll
  for (int nt = 0; nt < 4; ++nt)
    #pragma unroll
    for (int j = 0; j < 4; ++j) {
      int qg = rb + wid * 16 + lg * 4 + j;
      if (qg < NQtot)
        xab[(long long)(b * xa_bs + xa_off + qg) * xa_rs + h * DHD + nt * 16 + l15] =
            f2bfu(o[nt][j]);
    }
}

// ---- f32 attention for template rows (q<64): round-8 exact -----------------
__global__ __launch_bounds__(1024) void attn_tmpl(
    const float* __restrict__ qt, const float* __restrict__ kf,
    const unsigned short* __restrict__ vb,
    unsigned short* __restrict__ xab, float* __restrict__ probs,
    float* __restrict__ atp)
{
  constexpr int VST = NN + 4;
  __shared__ float ksh[NN * 65];
  __shared__ unsigned short vsh[64 * VST];
  __shared__ float pss[16][NN];
  __shared__ float qsh[16][64];
  int bh = blockIdx.x, b = bh / HH, h = bh % HH;
  int t = threadIdx.x;
  for (int i = t; i < NN * 64; i += 1024) {
    int rr = i >> 6, d = i & 63;
    long long gi = (long long)(b * NN + rr);
    ksh[rr * 65 + d] = kf[gi * 768 + h * DHD + d];
    vsh[d * VST + rr] = vb[gi * 1536 + h * DHD + d];
  }
  __syncthreads();
  int wid = t >> 6, lane = t & 63;
  float at[4] = {};
  for (int q = wid; q < NT; q += 16) {
    qsh[wid][lane] = qt[(long long)(b * NT + q) * 768 + h * DHD + lane];
    float s[5];
    #pragma unroll
    for (int r = 0; r < 5; ++r) s[r] = 0.f;
    const float* kp = ksh + lane * 65;
    #pragma unroll 16
    for (int d = 0; d < 64; ++d) {
      float qd = qsh[wid][d];
      #pragma unroll
      for (int r = 0; r < 5; ++r)
        s[r] = fmaf(qd, kp[(r << 6) * 65 + d], s[r]);
    }
    float m = -3.4e38f;
    #pragma unroll
    for (int r = 0; r < 5; ++r) { s[r] *= 0.125f; m = fmaxf(m, s[r]); }
    #pragma unroll
    for (int off = 32; off > 0; off >>= 1) m = fmaxf(m, __shfl_xor(m, off));
    float ss = 0.f;
    #pragma unroll
    for (int r = 0; r < 5; ++r) { s[r] = __expf(s[r] - m); ss += s[r]; }
    #pragma unroll
    for (int off = 32; off > 0; off >>= 1) ss += __shfl_xor(ss, off);
    float inv = 1.f / ss;
    long long pb = ((long long)(bh * NN) + q) * NN;
    #pragma unroll
    for (int r = 0; r < 5; ++r) {
      float p = s[r] * inv;
      s[r] = p;
      pss[wid][lane + (r << 6)] = p;
      probs[pb + lane + (r << 6)] = p;
    }
    #pragma unroll
    for (int r = 1; r < 5; ++r) at[r - 1] += s[r];
    float acc = 0.f;
    const unsigned short* vp = vsh + lane * VST;
    #pragma unroll 8
    for (int j = 0; j < NN; j += 4) {
      float4 p4 = *reinterpret_cast<const float4*>(&pss[wid][j]);
      ushort4 v4 = *reinterpret_cast<const ushort4*>(&vp[j]);
      acc = fmaf(p4.x, bf2f(v4.x), acc);
      acc = fmaf(p4.y, bf2f(v4.y), acc);
      acc = fmaf(p4.z, bf2f(v4.z), acc);
      acc = fmaf(p4.w, bf2f(v4.w), acc);
    }
    xab[(long long)(b * NN + q) * 768 + h * DHD + lane] = f2bfu(acc);
  }
  #pragma unroll
  for (int r = 1; r < 5; ++r) pss[wid][lane + ((r - 1) << 6)] = at[r - 1];
  __syncthreads();
  if (t < 256) {
    float v = 0.f;
    #pragma unroll
    for (int w = 0; w < 16; ++w) v += pss[w][t];
    atp[(long long)bh * 256 + t] = v;
  }
}

// ---- Per-batch argsort(-attn_t), stable; emit keep/removed -----------------
__global__ __launch_bounds__(256) void sort_kernel(
    const float* __restrict__ atp, const int* __restrict__ gis,
    float* __restrict__ keep_out, float* __restrict__ rem_out,
    int* __restrict__ topk)
{
  int b = blockIdx.x, t = threadIdx.x;
  __shared__ float sv[256];
  __shared__ int   si[256];
  float v = 0.f;
  for (int h = 0; h < HH; ++h) v += atp[((long long)(b * HH + h) << 8) + t];
  sv[t] = v; si[t] = t;
  __syncthreads();
  for (int k = 2; k <= 256; k <<= 1) {
    for (int j = k >> 1; j > 0; j >>= 1) {
      int ixj = t ^ j;
      if (ixj > t) {
        float va = sv[t], vb2 = sv[ixj];
        int ia = si[t], ib = si[ixj];
        bool after = (va < vb2) || (va == vb2 && ia > ib);
        bool dirUp = ((t & k) == 0);
        if (after == dirUp) { sv[t] = vb2; sv[ixj] = va; si[t] = ib; si[ixj] = ia; }
      }
      __syncthreads();
    }
  }
  int o = si[t];
  if (t < LK) {
    topk[b * LK + t] = o;
    keep_out[b * LK + t] = (float)gis[(b << 8) + o];
  } else {
    rem_out[b * NREM + (t - LK)] = (float)gis[(b << 8) + o];
  }
}

__global__ __launch_bounds__(256) void gather_kernel(
    const float* __restrict__ x1, const int* __restrict__ topk, float* __restrict__ x2)
{
  int r = blockIdx.x, t = threadIdx.x;
  int b = r / 244, rr = r % 244;
  int src = (rr < NT) ? rr : (NT + topk[b * LK + (rr - NT)]);
  const float* s = x1 + (long long)(b * NN + src) * DD;
  float* d = x2 + (long long)r * DD;
  d[t] = s[t]; d[256 + t] = s[256 + t]; d[512 + t] = s[512 + t];
}

__global__ void git_kernel(const int* __restrict__ git, float* __restrict__ o)
{
  int i = blockIdx.x * 256 + threadIdx.x;
  if (i < BB * NT) o[i] = (float)git[i];
}

extern "C" void kernel_launch(void* const* d_in, const int* in_sizes, int n_in,
                              void* d_out, int out_size, void* d_ws, size_t ws_size,
                              hipStream_t stream) {
  (void)in_sizes; (void)n_in; (void)out_size; (void)ws_size;
  const float* x    = (const float*)d_in[0];
  const float* ps   = (const float*)d_in[1];
  const int*   git  = (const int*)d_in[2];
  const int*   gis  = (const int*)d_in[3];
  const float* g1   = (const float*)d_in[4];
  const float* b1   = (const float*)d_in[5];
  const float* Wqkv = (const float*)d_in[6];
  const float* Wproj= (const float*)d_in[7];
  const float* bproj= (const float*)d_in[8];
  const float* gt   = (const float*)d_in[9];
  const float* bt   = (const float*)d_in[10];
  const float* Wq   = (const float*)d_in[11];
  const float* Wk   = (const float*)d_in[12];
  const float* Wv   = (const float*)d_in[13];
  const float* Wtp  = (const float*)d_in[14];
  const float* btp  = (const float*)d_in[15];
  const float* g2   = (const float*)d_in[16];
  const float* b2   = (const float*)d_in[17];
  const float* W1   = (const float*)d_in[18];
  const float* b1m  = (const float*)d_in[19];
  const float* W2   = (const float*)d_in[20];
  const float* b2m  = (const float*)d_in[21];
  float* wsf = (float*)d_ws;
  float* out = (float*)d_out;
  unsigned short* WQVT = (unsigned short*)(wsf + OFF_WQVT);
  unsigned short* QVp  = (unsigned short*)(wsf + OFF_QV);
  unsigned short* XAp  = (unsigned short*)(wsf + OFF_XA);
  unsigned short* WSMp = (unsigned short*)(wsf + OFF_WSM);
  unsigned short* WTS2 = (unsigned short*)(wsf + OFF_WTS2);
  unsigned short* SNp  = (unsigned short*)(wsf + OFF_SN);
  unsigned short* QT2p = (unsigned short*)(wsf + OFF_QT2);
  unsigned short* KTp  = (unsigned short*)(wsf + OFF_KT);
  unsigned short* VTp  = (unsigned short*)(wsf + OFF_VT);
  unsigned short* SAp  = (unsigned short*)(wsf + OFF_SA);
  unsigned short* H2p  = (unsigned short*)(wsf + OFF_H2);
  unsigned short* MIDp = (unsigned short*)(wsf + OFF_MIDB);
  #define WSLOT(i) (WSMp + (long long)(i) * 768 * 768)

  // S0a: Wqkv q-part (cols 0..767) and v-part (cols 1536..2303) -> 2 planes
  hipLaunchKernelGGL(cvt_wt, dim3(24, 24, 2), dim3(256), 0, stream,
                     Wqkv, WQVT, DD, 3 * DD, 0, 1536, (long long)768 * 768);
  // S0b: 5 small weights -> transposed planes
  hipLaunchKernelGGL(cvt_w5, dim3(24, 24, 5), dim3(256), 0, stream,
                     Wproj, Wq, Wk, Wv, Wtp, WSMp);
  // S1: h = LN(x) -> f32
  hipLaunchKernelGGL((ln_kernel<0>), dim3(BB * NN), dim3(256), 0, stream,
                     x, wsf + OFF_HF, (unsigned short*)nullptr, g1, b1, BB * NN, 0LL, 0);
  // S2a: k = h @ Wqkv[:,768:1536]  (f32, exact; 512-thr)
  hipLaunchKernelGGL(gemm_k, dim3(6, 80), dim3(512), 0, stream,
                     wsf + OFF_HF, BB * NN, 0LL, Wqkv + 768, 3 * DD,
                     wsf + OFF_KF, DD, BB * NN, DD);
  // S2b: q_template = h[template rows] @ Wqkv[:,0:768]  (f32, exact; 512-thr)
  hipLaunchKernelGGL(gemm_k, dim3(6, 16), dim3(512), 0, stream,
                     wsf + OFF_HF, NT, (long long)NN * DD, Wqkv, 3 * DD,
                     wsf + OFF_QTF, DD, BB * NT, DD);
  // S2c: [q|v] = h @ [Wq-part|Wv-part]  (MFMA bf16)
  hipLaunchKernelGGL((gemm_mfma<1>), dim3(12, 80), dim3(256), 0, stream,
                     (const void*)(wsf + OFF_HF), WQVT,
                     (const float*)nullptr, (const float*)nullptr,
                     (float*)nullptr, 1, QVp, 1536, 0,
                     BB * NN, 1536, DD, BB * NN, 0LL, 0, 0);
  // S3B: MFMA attention rows 64..319 -> probs, xa  (round-8 exact)
  hipLaunchKernelGGL((attn_mfma<NN, 8, 1, 1>), dim3(BB * HH, 2), dim3(512), 0, stream,
                     QVp, 1536, NN, NT,
                     (const void*)(wsf + OFF_KF), DD,
                     QVp + 768, 1536,
                     XAp, DD, NN, NT,
                     out + O_ATTN, 256);
  // S3A: f32 attention rows <64 -> probs, xa, attn_t  (round-8 exact)
  hipLaunchKernelGGL(attn_tmpl, dim3(BB * HH), dim3(1024), 0, stream,
                     wsf + OFF_QTF, wsf + OFF_KF, QVp + 768,
                     XAp, out + O_ATTN, wsf + OFF_ATP);
  // S4: x1 = x + xa @ Wproj + bproj
  hipLaunchKernelGGL((gemm_mfma<0>), dim3(6, 80), dim3(256), 0, stream,
                     (const void*)XAp, WSLOT(0), bproj, x,
                     wsf + OFF_X1, DD, (unsigned short*)nullptr, 1, DD,
                     BB * NN, DD, DD, BB * NN, 0LL, 0, 0);
  // S5/S6/S7
  hipLaunchKernelGGL(sort_kernel, dim3(BB), dim3(256), 0, stream,
                     wsf + OFF_ATP, gis, out + O_KEEP, out + O_REM,
                     (int*)(wsf + OFF_TOPK));
  hipLaunchKernelGGL(git_kernel, dim3((BB * NT + 255) / 256), dim3(256), 0, stream,
                     git, out + O_GIT);
  hipLaunchKernelGGL(gather_kernel, dim3(BB * 244), dim3(256), 0, stream,
                     wsf + OFF_X1, (const int*)(wsf + OFF_TOPK), wsf + OFF_X2);
  // S8: sn = LN(s) -> bf16
  hipLaunchKernelGGL((ln_kernel<1>), dim3(BB * LK), dim3(256), 0, stream,
                     wsf + OFF_X2, (float*)nullptr, SNp, gt, bt, LK, (long long)244 * DD, NT);
  // S9: qT = sn @ Wq -> bf16
  hipLaunchKernelGGL((gemm_mfma<0>), dim3(6, 45), dim3(256), 0, stream,
                     (const void*)SNp, WSLOT(1), (const float*)nullptr, (const float*)nullptr,
                     (float*)nullptr, 1, QT2p, DD, 0,
                     BB * LK, DD, DD, BB * LK, 0LL, 0, 0);
  // S10: kT = ps @ Wk -> bf16 (f32 A staged)
  hipLaunchKernelGGL((gemm_mfma<1>), dim3(6, 64), dim3(256), 0, stream,
                     (const void*)ps, WSLOT(2), (const float*)nullptr, (const float*)nullptr,
                     (float*)nullptr, 1, KTp, DD, 0,
                     BB * NPS, DD, DD, BB * NPS, 0LL, 0, 0);
  // S11: vT = ps @ Wv -> bf16
  hipLaunchKernelGGL((gemm_mfma<1>), dim3(6, 64), dim3(256), 0, stream,
                     (const void*)ps, WSLOT(3), (const float*)nullptr, (const float*)nullptr,
                     (float*)nullptr, 1, VTp, DD, 0,
                     BB * NPS, DD, DD, BB * NPS, 0LL, 0, 0);
  // S12: stage-2 attention (MFMA) -> sa bf16  (round-8 exact)
  hipLaunchKernelGGL((attn_mfma<NPS, 8, 0, 0>), dim3(BB * HH, 2), dim3(512), 0, stream,
                     QT2p, DD, LK, 0,
                     (const void*)KTp, DD,
                     VTp, DD,
                     SAp, DD, LK, 0,
                     (float*)nullptr, LK);
  // S13: s2 = s + sa @ Wtp + btp (into x2 rows 64..243)
  hipLaunchKernelGGL((gemm_mfma<0>), dim3(6, 45), dim3(256), 0, stream,
                     (const void*)SAp, WSLOT(4), btp, wsf + OFF_X2,
                     wsf + OFF_X2, DD, (unsigned short*)nullptr, 1, DD,
                     BB * LK, DD, DD, LK, (long long)244 * DD, NT, 0);
  // S14: h2 = LN(x2) -> bf16
  hipLaunchKernelGGL((ln_kernel<1>), dim3(BB * 244), dim3(256), 0, stream,
                     wsf + OFF_X2, (float*)nullptr, H2p, g2, b2, BB * 244, 0LL, 0);
  // S15: mid = gelu(h2 @ W1 + b1m) -> bf16
  hipLaunchKernelGGL(cvt_wt, dim3(96, 24, 1), dim3(256), 0, stream,
                     W1, WTS2, DD, 4 * DD, 0, 0, 0LL);
  hipLaunchKernelGGL((gemm_mfma<0>), dim3(24, 61), dim3(256), 0, stream,
                     (const void*)H2p, WTS2, b1m, (const float*)nullptr,
                     (float*)nullptr, 1, MIDp, 4 * DD, 0,
                     BB * 244, 4 * DD, DD, BB * 244, 0LL, 0, 1);
  // S16: x_out = x2 + mid @ W2 + b2m -> f32 d_out
  hipLaunchKernelGGL(cvt_wt, dim3(24, 96, 1), dim3(256), 0, stream,
                     W2, WTS2, 4 * DD, DD, 0, 0, 0LL);
  hipLaunchKernelGGL((gemm_mfma<0>), dim3(6, 61), dim3(256), 0, stream,
                     (const void*)MIDp, WTS2, b2m, wsf + OFF_X2,
                     out + O_X, DD, (unsigned short*)nullptr, 1, DD,
                     BB * 244, DD, 4 * DD, BB * 244, 0LL, 0, 0);
}

// Round 11
// 1036.904 us; speedup vs baseline: 5.0667x; 1.0399x over previous
//
#include <hip/hip_runtime.h>
#include <hip/hip_bf16.h>

// Problem constants
#define BB 32
#define NT 64
#define NS 256
#define NN 320
#define NPS 256
#define DD 768
#define HH 12
#define DHD 64
#define LK 180
#define NREM 76

// ws layout (float-element offsets). Peak 32.18M f = 128.7MB (same as r10).
#define OFF_HF    0LL          // f32 [10240][768]  S1-S2c
#define OFF_KF    7864320LL    // f32 [10240][768]  S2a-S3
#define OFF_QTF   15728640LL   // f32 [2048][768]   S2b-S3A
#define OFF_QV    17301504LL   // bf16[10240][1536] S2c-S3
#define OFF_WQVT  25165824LL   // bf16 2x[768][768] S0-S2c
#define OFF_HB    26000000LL   // bf16[10240][768]  S1-S2c (dead before VT)
#define OFF_XA    0LL          // bf16[10240][768]  S3-S4 (HF dead)
#define OFF_X1    12000000LL   // f32 [10240][768]  S4-S7
#define OFF_X2    0LL          // f32 [7808][768]   S7-S16
#define OFF_SN    6000000LL    // bf16[5760][768]   S8-S9
#define OFF_PSB   17301504LL   // bf16[8192][768]   S7.5-S11 (QV dead)
#define OFF_QT2   20500000LL   // bf16[5760][768]   S9-S12
#define OFF_KT    22800000LL   // bf16[8192][768]   S10-S12
#define OFF_VT    26000000LL   // bf16[8192][768]   S11-S12 (HB dead)
#define OFF_SA    6000000LL    // bf16[5760][768]   S12-S13 (SN dead)
#define OFF_H2    12000000LL   // bf16[7808][768]   S14-S15 (X1 dead)
#define OFF_MIDB  15000000LL   // bf16[7808][3072]  S15-S16 (QT2/KT/VT dead)
#define OFF_WTS2  29300000LL   // bf16 W1t/W2t serial slot
#define OFF_ATP   30500000LL   // f32 384*256
#define OFF_TOPK  30600000LL   // int 5760
#define OFF_WSM   30700000LL   // bf16 5x[768][768] small weights (whole launch)

// d_out (f32) offsets: (x, git, keep, removed, attn)
#define O_X    0LL
#define O_GIT  5996544LL
#define O_KEEP 5998592LL
#define O_REM  6004352LL
#define O_ATTN 6006784LL

typedef __attribute__((ext_vector_type(8))) short short8v;
typedef __attribute__((ext_vector_type(4))) float f32x4;

__device__ __forceinline__ float bf2f(unsigned short u) {
  return __uint_as_float((unsigned)u << 16);
}
__device__ __forceinline__ unsigned short f2bfu(float f) {
  __hip_bfloat16 h = __float2bfloat16(f);
  return *reinterpret_cast<unsigned short*>(&h);
}
// async global->LDS, 16B per lane; lds base must be wave-uniform.
__device__ __forceinline__ void gload16(const unsigned short* g, unsigned short* l) {
  __builtin_amdgcn_global_load_lds(
      (const __attribute__((address_space(1))) unsigned int*)g,
      (__attribute__((address_space(3))) unsigned int*)l, 16, 0, 0);
}

// ---------------- LayerNorm. OMODE: 0=f32, 1=bf16, 3=both -------------------
template<int OMODE>
__global__ __launch_bounds__(256) void ln_kernel(
    const float* __restrict__ in, float* __restrict__ outf,
    unsigned short* __restrict__ outh,
    const float* __restrict__ g, const float* __restrict__ b,
    int rpb, long long bstride, int row0)
{
  int r = blockIdx.x, t = threadIdx.x;
  long long base = (long long)(r / rpb) * bstride + (long long)(r % rpb + row0) * DD;
  float v0 = in[base + t], v1 = in[base + 256 + t], v2 = in[base + 512 + t];
  __shared__ float red[256];
  red[t] = v0 + v1 + v2;
  __syncthreads();
  #pragma unroll
  for (int off = 128; off > 0; off >>= 1) { if (t < off) red[t] += red[t + off]; __syncthreads(); }
  float mean = red[0] * (1.f / 768.f);
  __syncthreads();
  float d0 = v0 - mean, d1 = v1 - mean, d2 = v2 - mean;
  red[t] = d0 * d0 + d1 * d1 + d2 * d2;
  __syncthreads();
  #pragma unroll
  for (int off = 128; off > 0; off >>= 1) { if (t < off) red[t] += red[t + off]; __syncthreads(); }
  float rstd = rsqrtf(red[0] * (1.f / 768.f) + 1e-5f);
  long long ob = (long long)r * DD;
  float o0 = d0 * rstd * g[t]       + b[t];
  float o1 = d1 * rstd * g[256 + t] + b[256 + t];
  float o2 = d2 * rstd * g[512 + t] + b[512 + t];
  if (OMODE == 0 || OMODE == 3) {
    outf[ob + t] = o0; outf[ob + 256 + t] = o1; outf[ob + 512 + t] = o2;
  }
  if (OMODE == 1 || OMODE == 3) {
    outh[ob + t] = f2bfu(o0); outh[ob + 256 + t] = f2bfu(o1); outh[ob + 512 + t] = f2bfu(o2);
  }
}

// ------ Transpose+convert: W f32 [K][Nfull] -> bf16 [N][K]; z-planes --------
__global__ __launch_bounds__(256) void cvt_wt(
    const float* __restrict__ W, unsigned short* __restrict__ Th,
    int K, int Nfull, int n0off, int zoff, long long zdststep)
{
  __shared__ float tile[32][33];
  int z = blockIdx.z;
  unsigned short* T = Th + (long long)z * zdststep;
  int ncol = n0off + z * zoff;
  int n0 = blockIdx.x * 32, k0 = blockIdx.y * 32;
  int tx = threadIdx.x & 31, ty4 = (threadIdx.x >> 5) * 4;
  #pragma unroll
  for (int i = 0; i < 4; ++i)
    tile[ty4 + i][tx] = W[(long long)(k0 + ty4 + i) * Nfull + ncol + n0 + tx];
  __syncthreads();
  #pragma unroll
  for (int i = 0; i < 4; ++i)
    T[(long long)(n0 + ty4 + i) * K + k0 + tx] = f2bfu(tile[tx][ty4 + i]);
}

// ------ 5 small weights [768][768] -> bf16 [768][768]^T planes --------------
__global__ __launch_bounds__(256) void cvt_w5(
    const float* __restrict__ Wa, const float* __restrict__ Wb,
    const float* __restrict__ Wc, const float* __restrict__ Wd,
    const float* __restrict__ We, unsigned short* __restrict__ Th)
{
  __shared__ float tile[32][33];
  const float* srcs[5] = {Wa, Wb, Wc, Wd, We};
  const float* W = srcs[blockIdx.z];
  unsigned short* T = Th + (long long)blockIdx.z * (768 * 768);
  int n0 = blockIdx.x * 32, k0 = blockIdx.y * 32;
  int tx = threadIdx.x & 31, ty4 = (threadIdx.x >> 5) * 4;
  #pragma unroll
  for (int i = 0; i < 4; ++i)
    tile[ty4 + i][tx] = W[(long long)(k0 + ty4 + i) * 768 + n0 + tx];
  __syncthreads();
  #pragma unroll
  for (int i = 0; i < 4; ++i)
    T[(long long)(n0 + ty4 + i) * 768 + k0 + tx] = f2bfu(tile[tx][ty4 + i]);
}

// ---------------- f32 -> bf16 copy (vectorized) -----------------------------
__global__ __launch_bounds__(256) void cvt_bf_kernel(
    const float* __restrict__ in, unsigned short* __restrict__ out, long long n)
{
  long long i = ((long long)blockIdx.x * 256 + threadIdx.x) * 4;
  if (i < n) {
    float4 v = *reinterpret_cast<const float4*>(&in[i]);
    ushort4 o;
    o.x = f2bfu(v.x); o.y = f2bfu(v.y); o.z = f2bfu(v.z); o.w = f2bfu(v.w);
    *reinterpret_cast<ushort4*>(&out[i]) = o;
  }
}

// -------- f32 vector GEMM (order-critical): 512 thr, reg-prefetch dbuf ------
// Per-output accumulation order identical to round-10 (kk ascending).
__global__ __launch_bounds__(512) void gemm_k(
    const float* __restrict__ A, int a_rpb, long long a_bstride,
    const float* __restrict__ W, int wst,
    float* __restrict__ Cf, int c_ld, int M, int K)
{
  __shared__ float As[16][132];
  __shared__ float Ws[16][132];
  int t = threadIdx.x;
  long long bm = (long long)blockIdx.y * 128;
  long long bn = (long long)blockIdx.x * 128;
  float acc[4][8] = {};
  int wid = t >> 6, lane = t & 63;
  int tm = (wid & 3) * 32 + (lane >> 3) * 4;
  int tn = (wid >> 2) * 64 + (lane & 7) * 8;
  int idx = t << 2;
  int am = idx >> 4, ak = idx & 15;
  int wk = idx >> 7, wn2 = idx & 127;
  long long r = bm + am;
  long long abase = (r / a_rpb) * a_bstride + (r % a_rpb) * (long long)K;
  float4 a4 = *reinterpret_cast<const float4*>(A + abase + ak);
  float4 w4 = *reinterpret_cast<const float4*>(W + (long long)wk * wst + bn + wn2);
  for (int k0 = 0; k0 < K; k0 += 16) {
    As[ak + 0][am] = a4.x; As[ak + 1][am] = a4.y;
    As[ak + 2][am] = a4.z; As[ak + 3][am] = a4.w;
    *reinterpret_cast<float4*>(&Ws[wk][wn2]) = w4;
    __syncthreads();
    if (k0 + 16 < K) {     // prefetch next tile; overlaps FMA block below
      a4 = *reinterpret_cast<const float4*>(A + abase + k0 + 16 + ak);
      w4 = *reinterpret_cast<const float4*>(W + (long long)(k0 + 16 + wk) * wst + bn + wn2);
    }
    #pragma unroll
    for (int kk = 0; kk < 16; ++kk) {
      float a[4], w[8];
      *reinterpret_cast<float4*>(a)     = *reinterpret_cast<const float4*>(&As[kk][tm]);
      *reinterpret_cast<float4*>(w)     = *reinterpret_cast<const float4*>(&Ws[kk][tn]);
      *reinterpret_cast<float4*>(w + 4) = *reinterpret_cast<const float4*>(&Ws[kk][tn + 4]);
      #pragma unroll
      for (int i = 0; i < 4; ++i)
        #pragma unroll
        for (int j = 0; j < 8; ++j)
          acc[i][j] = fmaf(a[i], w[j], acc[i][j]);
    }
    __syncthreads();
  }
  #pragma unroll
  for (int i = 0; i < 4; ++i) {
    long long crow = (bm + tm + i) * c_ld;
    #pragma unroll
    for (int j = 0; j < 8; ++j)
      Cf[crow + bn + tn + j] = acc[i][j];
  }
}

// -------- MFMA GEMM v2 (m97 pattern): global_load_lds + linear LDS ----------
// A,Bt bf16; Bt pre-transposed [N][K]. 128x128x32 tile, 4 waves, 16x16x32.
__global__ __launch_bounds__(256) void gemm_mfma(
    const unsigned short* __restrict__ A, const unsigned short* __restrict__ Bt,
    const float* __restrict__ bias, const float* __restrict__ resid,
    float* __restrict__ Cf, int ldf,
    unsigned short* __restrict__ Cb, int ldb, int colsplit,
    int M, int N, int K,
    int c_rpb, long long c_bstride, int c_row0, int act)
{
  __shared__ unsigned short As[128 * 32], Bs[128 * 32];
  int t = threadIdx.x;
  long long bm = (long long)blockIdx.y * 128;
  long long bn = (long long)blockIdx.x * 128;
  int wid = t >> 6, lane = t & 63;
  int wr = (wid >> 1) << 6, wc = (wid & 1) << 6;
  // staging: round l, wave w covers elements [(l*4+w)*512, +512) (1024B/wave)
  int e0 = (wid << 9) + lane * 8;
  int e1 = ((4 + wid) << 9) + lane * 8;
  int r0 = e0 >> 5, c0 = e0 & 31;
  int r1 = e1 >> 5, c1 = e1 & 31;
  unsigned short* As0 = &As[(long long)(wid << 9)];
  unsigned short* As1 = &As[(long long)((4 + wid) << 9)];
  unsigned short* Bs0 = &Bs[(long long)(wid << 9)];
  unsigned short* Bs1 = &Bs[(long long)((4 + wid) << 9)];
  const unsigned short* Ar0 = A + (bm + r0) * (long long)K + c0;
  const unsigned short* Ar1 = A + (bm + r1) * (long long)K + c1;
  const unsigned short* Br0 = Bt + (bn + r0) * (long long)K + c0;
  const unsigned short* Br1 = Bt + (bn + r1) * (long long)K + c1;
  f32x4 acc[4][4];
  #pragma unroll
  for (int m = 0; m < 4; ++m)
    #pragma unroll
    for (int n = 0; n < 4; ++n) acc[m][n] = (f32x4){0.f, 0.f, 0.f, 0.f};
  int ra = (wr + (lane & 15)) * 32 + ((lane >> 4) << 3);
  int rb = (wc + (lane & 15)) * 32 + ((lane >> 4) << 3);
  for (int k0 = 0; k0 < K; k0 += 32) {
    gload16(Ar0 + k0, As0);
    gload16(Ar1 + k0, As1);
    gload16(Br0 + k0, Bs0);
    gload16(Br1 + k0, Bs1);
    __syncthreads();
    short8v a[4], b[4];
    #pragma unroll
    for (int m = 0; m < 4; ++m) {
      a[m] = *reinterpret_cast<const short8v*>(&As[ra + m * 512]);
      b[m] = *reinterpret_cast<const short8v*>(&Bs[rb + m * 512]);
    }
    #pragma unroll
    for (int m = 0; m < 4; ++m)
      #pragma unroll
      for (int n = 0; n < 4; ++n)
        acc[m][n] = __builtin_amdgcn_mfma_f32_16x16x32_bf16(a[m], b[n], acc[m][n], 0, 0, 0);
    __syncthreads();
  }
  int ro = (lane >> 4) << 2, co = lane & 15;
  #pragma unroll
  for (int m = 0; m < 4; ++m) {
    #pragma unroll
    for (int j = 0; j < 4; ++j) {
      long long r = bm + wr + m * 16 + ro + j;
      long long base = (r / c_rpb) * c_bstride + (long long)((int)(r % c_rpb) + c_row0) * ldf;
      #pragma unroll
      for (int n = 0; n < 4; ++n) {
        long long c = bn + wc + n * 16 + co;
        float v = acc[m][n][j];
        if (bias) v += bias[c];
        if (act) v = 0.5f * v * (1.f + erff(v * 0.70710678118654752f));
        if (resid) v += resid[base + c];
        if (c < colsplit) Cf[base + c] = v;
        else Cb[r * ldb + (c - colsplit)] = f2bfu(v);
      }
    }
  }
}

// ======== MFMA flash attention (value path) — round-8 exact =================
template<int NKV, int NW, int PROBS, int KF32>
__global__ __launch_bounds__(NW * 64) void attn_mfma(
    const unsigned short* __restrict__ q, int q_rs, int q_bs, int q_off,
    const void* __restrict__ kv, int k_rs,
    const unsigned short* __restrict__ v, int v_rs,
    unsigned short* __restrict__ xab, int xa_rs, int xa_bs, int xa_off,
    float* __restrict__ probs, int NQtot)
{
  constexpr int KST = 68;
  constexpr int VST = NKV + 4;
  constexpr int NT_K = NKV / 16;
  constexpr int NTH = NW * 64;
  __shared__ unsigned short ksh[NKV * KST];
  __shared__ unsigned short qsh[NW * 16 * KST];
  __shared__ unsigned short vsh[64 * VST];
  __shared__ float ldsT[PROBS ? NW * 16 * 17 : 1];
  int bh = blockIdx.x, b = bh / HH, h = bh % HH;
  int rb = blockIdx.y * (NW * 16);
  int t = threadIdx.x;
  const float* kf = (const float*)kv;
  const unsigned short* ku = (const unsigned short*)kv;
  for (int i = t; i < NKV * 64; i += NTH) {
    int kr = i >> 6, d = i & 63;
    long long gi = (long long)(b * NKV + kr);
    ksh[kr * KST + d] = KF32 ? f2bfu(kf[gi * k_rs + h * DHD + d])
                             : ku[gi * k_rs + h * DHD + d];
    int kp = (kr & ~31) | (((kr >> 2) & 3) << 3) | (((kr >> 4) & 1) << 2) | (kr & 3);
    vsh[d * VST + kp] = v[gi * v_rs + h * DHD + d];
  }
  for (int i = t; i < NW * 16 * 64; i += NTH) {
    int qr = i >> 6, d = i & 63;
    int qg = rb + qr;
    qsh[qr * KST + d] = (qg < NQtot)
      ? q[(long long)(b * q_bs + q_off + qg) * q_rs + h * DHD + d] : (unsigned short)0;
  }
  __syncthreads();
  int wid = t >> 6, lane = t & 63;
  int l15 = lane & 15, lg = lane >> 4;
  short8v bq[2];
  #pragma unroll
  for (int ks = 0; ks < 2; ++ks)
    bq[ks] = *reinterpret_cast<const short8v*>(&qsh[(wid * 16 + l15) * KST + ks * 32 + lg * 8]);
  f32x4 s[NT_K];
  #pragma unroll
  for (int mt = 0; mt < NT_K; ++mt) s[mt] = (f32x4){0.f, 0.f, 0.f, 0.f};
  #pragma unroll
  for (int mt = 0; mt < NT_K; ++mt)
    #pragma unroll
    for (int ks = 0; ks < 2; ++ks) {
      short8v ka = *reinterpret_cast<const short8v*>(&ksh[(mt * 16 + l15) * KST + ks * 32 + lg * 8]);
      s[mt] = __builtin_amdgcn_mfma_f32_16x16x32_bf16(ka, bq[ks], s[mt], 0, 0, 0);
    }
  float m = -3.4e38f;
  #pragma unroll
  for (int mt = 0; mt < NT_K; ++mt)
    #pragma unroll
    for (int j = 0; j < 4; ++j) { s[mt][j] *= 0.125f; m = fmaxf(m, s[mt][j]); }
  m = fmaxf(m, __shfl_xor(m, 16)); m = fmaxf(m, __shfl_xor(m, 32));
  float ss = 0.f;
  #pragma unroll
  for (int mt = 0; mt < NT_K; ++mt)
    #pragma unroll
    for (int j = 0; j < 4; ++j) { s[mt][j] = __expf(s[mt][j] - m); ss += s[mt][j]; }
  ss += __shfl_xor(ss, 16); ss += __shfl_xor(ss, 32);
  float inv = 1.f / ss;
  #pragma unroll
  for (int mt = 0; mt < NT_K; ++mt)
    #pragma unroll
    for (int j = 0; j < 4; ++j) s[mt][j] *= inv;
  if (PROBS) {
    float* lT = &ldsT[wid * 16 * 17];
    #pragma unroll
    for (int mt = 0; mt < NT_K; ++mt) {
      #pragma unroll
      for (int j = 0; j < 4; ++j) lT[l15 * 17 + lg * 4 + j] = s[mt][j];
      #pragma unroll
      for (int m4 = 0; m4 < 4; ++m4) {
        int qg = rb + wid * 16 + m4 * 4 + lg;
        if (qg < NQtot)
          probs[((long long)(bh * q_bs + q_off + qg)) * NKV + mt * 16 + l15] =
              lT[(m4 * 4 + lg) * 17 + l15];
      }
    }
  }
  f32x4 o[4];
  #pragma unroll
  for (int nt = 0; nt < 4; ++nt) o[nt] = (f32x4){0.f, 0.f, 0.f, 0.f};
  #pragma unroll
  for (int c = 0; c < NKV / 32; ++c) {
    short8v a8;
    #pragma unroll
    for (int j = 0; j < 4; ++j) {
      a8[j]     = (short)f2bfu(s[2 * c][j]);
      a8[4 + j] = (short)f2bfu(s[2 * c + 1][j]);
    }
    #pragma unroll
    for (int nt = 0; nt < 4; ++nt) {
      short8v bv = *reinterpret_cast<const short8v*>(&vsh[(nt * 16 + l15) * VST + c * 32 + lg * 8]);
      o[nt] = __builtin_amdgcn_mfma_f32_16x16x32_bf16(a8, bv, o[nt], 0, 0, 0);
    }
  }
  #pragma unroll
  for (int nt = 0; nt < 4; ++nt)
    #pragma unroll
    for (int j = 0; j < 4; ++j) {
      int qg = rb + wid * 16 + lg * 4 + j;
      if (qg < NQtot)
        xab[(long long)(b * xa_bs + xa_off + qg) * xa_rs + h * DHD + nt * 16 + l15] =
            f2bfu(o[nt][j]);
    }
}

// ---- f32 attention for template rows (q<64): round-8 exact -----------------
__global__ __launch_bounds__(1024) void attn_tmpl(
    const float* __restrict__ qt, const float* __restrict__ kf,
    const unsigned short* __restrict__ vb,
    unsigned short* __restrict__ xab, float* __restrict__ probs,
    float* __restrict__ atp)
{
  constexpr int VST = NN + 4;
  __shared__ float ksh[NN * 65];
  __shared__ unsigned short vsh[64 * VST];
  __shared__ float pss[16][NN];
  __shared__ float qsh[16][64];
  int bh = blockIdx.x, b = bh / HH, h = bh % HH;
  int t = threadIdx.x;
  for (int i = t; i < NN * 64; i += 1024) {
    int rr = i >> 6, d = i & 63;
    long long gi = (long long)(b * NN + rr);
    ksh[rr * 65 + d] = kf[gi * 768 + h * DHD + d];
    vsh[d * VST + rr] = vb[gi * 1536 + h * DHD + d];
  }
  __syncthreads();
  int wid = t >> 6, lane = t & 63;
  float at[4] = {};
  for (int q = wid; q < NT; q += 16) {
    qsh[wid][lane] = qt[(long long)(b * NT + q) * 768 + h * DHD + lane];
    float s[5];
    #pragma unroll
    for (int r = 0; r < 5; ++r) s[r] = 0.f;
    const float* kp = ksh + lane * 65;
    #pragma unroll 16
    for (int d = 0; d < 64; ++d) {
      float qd = qsh[wid][d];
      #pragma unroll
      for (int r = 0; r < 5; ++r)
        s[r] = fmaf(qd, kp[(r << 6) * 65 + d], s[r]);
    }
    float m = -3.4e38f;
    #pragma unroll
    for (int r = 0; r < 5; ++r) { s[r] *= 0.125f; m = fmaxf(m, s[r]); }
    #pragma unroll
    for (int off = 32; off > 0; off >>= 1) m = fmaxf(m, __shfl_xor(m, off));
    float ss = 0.f;
    #pragma unroll
    for (int r = 0; r < 5; ++r) { s[r] = __expf(s[r] - m); ss += s[r]; }
    #pragma unroll
    for (int off = 32; off > 0; off >>= 1) ss += __shfl_xor(ss, off);
    float inv = 1.f / ss;
    long long pb = ((long long)(bh * NN) + q) * NN;
    #pragma unroll
    for (int r = 0; r < 5; ++r) {
      float p = s[r] * inv;
      s[r] = p;
      pss[wid][lane + (r << 6)] = p;
      probs[pb + lane + (r << 6)] = p;
    }
    #pragma unroll
    for (int r = 1; r < 5; ++r) at[r - 1] += s[r];
    float acc = 0.f;
    const unsigned short* vp = vsh + lane * VST;
    #pragma unroll 8
    for (int j = 0; j < NN; j += 4) {
      float4 p4 = *reinterpret_cast<const float4*>(&pss[wid][j]);
      ushort4 v4 = *reinterpret_cast<const ushort4*>(&vp[j]);
      acc = fmaf(p4.x, bf2f(v4.x), acc);
      acc = fmaf(p4.y, bf2f(v4.y), acc);
      acc = fmaf(p4.z, bf2f(v4.z), acc);
      acc = fmaf(p4.w, bf2f(v4.w), acc);
    }
    xab[(long long)(b * NN + q) * 768 + h * DHD + lane] = f2bfu(acc);
  }
  #pragma unroll
  for (int r = 1; r < 5; ++r) pss[wid][lane + ((r - 1) << 6)] = at[r - 1];
  __syncthreads();
  if (t < 256) {
    float v = 0.f;
    #pragma unroll
    for (int w = 0; w < 16; ++w) v += pss[w][t];
    atp[(long long)bh * 256 + t] = v;
  }
}

// ---- Per-batch argsort(-attn_t), stable; emit keep/removed -----------------
__global__ __launch_bounds__(256) void sort_kernel(
    const float* __restrict__ atp, const int* __restrict__ gis,
    float* __restrict__ keep_out, float* __restrict__ rem_out,
    int* __restrict__ topk)
{
  int b = blockIdx.x, t = threadIdx.x;
  __shared__ float sv[256];
  __shared__ int   si[256];
  float v = 0.f;
  for (int h = 0; h < HH; ++h) v += atp[((long long)(b * HH + h) << 8) + t];
  sv[t] = v; si[t] = t;
  __syncthreads();
  for (int k = 2; k <= 256; k <<= 1) {
    for (int j = k >> 1; j > 0; j >>= 1) {
      int ixj = t ^ j;
      if (ixj > t) {
        float va = sv[t], vb2 = sv[ixj];
        int ia = si[t], ib = si[ixj];
        bool after = (va < vb2) || (va == vb2 && ia > ib);
        bool dirUp = ((t & k) == 0);
        if (after == dirUp) { sv[t] = vb2; sv[ixj] = va; si[t] = ib; si[ixj] = ia; }
      }
      __syncthreads();
    }
  }
  int o = si[t];
  if (t < LK) {
    topk[b * LK + t] = o;
    keep_out[b * LK + t] = (float)gis[(b << 8) + o];
  } else {
    rem_out[b * NREM + (t - LK)] = (float)gis[(b << 8) + o];
  }
}

__global__ __launch_bounds__(256) void gather_kernel(
    const float* __restrict__ x1, const int* __restrict__ topk, float* __restrict__ x2)
{
  int r = blockIdx.x, t = threadIdx.x;
  int b = r / 244, rr = r % 244;
  int src = (rr < NT) ? rr : (NT + topk[b * LK + (rr - NT)]);
  const float* s = x1 + (long long)(b * NN + src) * DD;
  float* d = x2 + (long long)r * DD;
  d[t] = s[t]; d[256 + t] = s[256 + t]; d[512 + t] = s[512 + t];
}

__global__ void git_kernel(const int* __restrict__ git, float* __restrict__ o)
{
  int i = blockIdx.x * 256 + threadIdx.x;
  if (i < BB * NT) o[i] = (float)git[i];
}

extern "C" void kernel_launch(void* const* d_in, const int* in_sizes, int n_in,
                              void* d_out, int out_size, void* d_ws, size_t ws_size,
                              hipStream_t stream) {
  (void)in_sizes; (void)n_in; (void)out_size; (void)ws_size;
  const float* x    = (const float*)d_in[0];
  const float* ps   = (const float*)d_in[1];
  const int*   git  = (const int*)d_in[2];
  const int*   gis  = (const int*)d_in[3];
  const float* g1   = (const float*)d_in[4];
  const float* b1   = (const float*)d_in[5];
  const float* Wqkv = (const float*)d_in[6];
  const float* Wproj= (const float*)d_in[7];
  const float* bproj= (const float*)d_in[8];
  const float* gt   = (const float*)d_in[9];
  const float* bt   = (const float*)d_in[10];
  const float* Wq   = (const float*)d_in[11];
  const float* Wk   = (const float*)d_in[12];
  const float* Wv   = (const float*)d_in[13];
  const float* Wtp  = (const float*)d_in[14];
  const float* btp  = (const float*)d_in[15];
  const float* g2   = (const float*)d_in[16];
  const float* b2   = (const float*)d_in[17];
  const float* W1   = (const float*)d_in[18];
  const float* b1m  = (const float*)d_in[19];
  const float* W2   = (const float*)d_in[20];
  const float* b2m  = (const float*)d_in[21];
  float* wsf = (float*)d_ws;
  float* out = (float*)d_out;
  unsigned short* WQVT = (unsigned short*)(wsf + OFF_WQVT);
  unsigned short* HBp  = (unsigned short*)(wsf + OFF_HB);
  unsigned short* QVp  = (unsigned short*)(wsf + OFF_QV);
  unsigned short* XAp  = (unsigned short*)(wsf + OFF_XA);
  unsigned short* WSMp = (unsigned short*)(wsf + OFF_WSM);
  unsigned short* WTS2 = (unsigned short*)(wsf + OFF_WTS2);
  unsigned short* SNp  = (unsigned short*)(wsf + OFF_SN);
  unsigned short* PSBp = (unsigned short*)(wsf + OFF_PSB);
  unsigned short* QT2p = (unsigned short*)(wsf + OFF_QT2);
  unsigned short* KTp  = (unsigned short*)(wsf + OFF_KT);
  unsigned short* VTp  = (unsigned short*)(wsf + OFF_VT);
  unsigned short* SAp  = (unsigned short*)(wsf + OFF_SA);
  unsigned short* H2p  = (unsigned short*)(wsf + OFF_H2);
  unsigned short* MIDp = (unsigned short*)(wsf + OFF_MIDB);
  #define WSLOT(i) (WSMp + (long long)(i) * 768 * 768)

  // S0a: Wqkv q-part and v-part -> 2 transposed bf16 planes
  hipLaunchKernelGGL(cvt_wt, dim3(24, 24, 2), dim3(256), 0, stream,
                     Wqkv, WQVT, DD, 3 * DD, 0, 1536, (long long)768 * 768);
  // S0b: 5 small weights -> transposed planes
  hipLaunchKernelGGL(cvt_w5, dim3(24, 24, 5), dim3(256), 0, stream,
                     Wproj, Wq, Wk, Wv, Wtp, WSMp);
  // S1: h = LN(x) -> f32 HF + bf16 HB
  hipLaunchKernelGGL((ln_kernel<3>), dim3(BB * NN), dim3(256), 0, stream,
                     x, wsf + OFF_HF, HBp, g1, b1, BB * NN, 0LL, 0);
  // S2a: k = h @ Wqkv[:,768:1536]  (f32, exact; dbuf)
  hipLaunchKernelGGL(gemm_k, dim3(6, 80), dim3(512), 0, stream,
                     wsf + OFF_HF, BB * NN, 0LL, Wqkv + 768, 3 * DD,
                     wsf + OFF_KF, DD, BB * NN, DD);
  // S2b: q_template = h[template rows] @ Wqkv[:,0:768]  (f32, exact; dbuf)
  hipLaunchKernelGGL(gemm_k, dim3(6, 16), dim3(512), 0, stream,
                     wsf + OFF_HF, NT, (long long)NN * DD, Wqkv, 3 * DD,
                     wsf + OFF_QTF, DD, BB * NT, DD);
  // S2c: [q|v] = h(bf16) @ [Wq-part|Wv-part]  (MFMA v2)
  hipLaunchKernelGGL(gemm_mfma, dim3(12, 80), dim3(256), 0, stream,
                     HBp, WQVT, (const float*)nullptr, (const float*)nullptr,
                     (float*)nullptr, 1, QVp, 1536, 0,
                     BB * NN, 1536, DD, BB * NN, 0LL, 0, 0);
  // S3B: MFMA attention rows 64..319 -> probs, xa
  hipLaunchKernelGGL((attn_mfma<NN, 8, 1, 1>), dim3(BB * HH, 2), dim3(512), 0, stream,
                     QVp, 1536, NN, NT,
                     (const void*)(wsf + OFF_KF), DD,
                     QVp + 768, 1536,
                     XAp, DD, NN, NT,
                     out + O_ATTN, 256);
  // S3A: f32 attention rows <64 -> probs, xa, attn_t
  hipLaunchKernelGGL(attn_tmpl, dim3(BB * HH), dim3(1024), 0, stream,
                     wsf + OFF_QTF, wsf + OFF_KF, QVp + 768,
                     XAp, out + O_ATTN, wsf + OFF_ATP);
  // S4: x1 = x + xa @ Wproj + bproj
  hipLaunchKernelGGL(gemm_mfma, dim3(6, 80), dim3(256), 0, stream,
                     XAp, WSLOT(0), bproj, x,
                     wsf + OFF_X1, DD, (unsigned short*)nullptr, 1, DD,
                     BB * NN, DD, DD, BB * NN, 0LL, 0, 0);
  // S5/S6/S7
  hipLaunchKernelGGL(sort_kernel, dim3(BB), dim3(256), 0, stream,
                     wsf + OFF_ATP, gis, out + O_KEEP, out + O_REM,
                     (int*)(wsf + OFF_TOPK));
  hipLaunchKernelGGL(git_kernel, dim3((BB * NT + 255) / 256), dim3(256), 0, stream,
                     git, out + O_GIT);
  hipLaunchKernelGGL(gather_kernel, dim3(BB * 244), dim3(256), 0, stream,
                     wsf + OFF_X1, (const int*)(wsf + OFF_TOPK), wsf + OFF_X2);
  // S7.5: ps -> bf16 (QV region is dead now)
  hipLaunchKernelGGL(cvt_bf_kernel, dim3(6144), dim3(256), 0, stream,
                     ps, PSBp, (long long)BB * NPS * DD);
  // S8: sn = LN(s) -> bf16
  hipLaunchKernelGGL((ln_kernel<1>), dim3(BB * LK), dim3(256), 0, stream,
                     wsf + OFF_X2, (float*)nullptr, SNp, gt, bt, LK, (long long)244 * DD, NT);
  // S9: qT = sn @ Wq -> bf16
  hipLaunchKernelGGL(gemm_mfma, dim3(6, 45), dim3(256), 0, stream,
                     SNp, WSLOT(1), (const float*)nullptr, (const float*)nullptr,
                     (float*)nullptr, 1, QT2p, DD, 0,
                     BB * LK, DD, DD, BB * LK, 0LL, 0, 0);
  // S10: kT = ps @ Wk -> bf16
  hipLaunchKernelGGL(gemm_mfma, dim3(6, 64), dim3(256), 0, stream,
                     PSBp, WSLOT(2), (const float*)nullptr, (const float*)nullptr,
                     (float*)nullptr, 1, KTp, DD, 0,
                     BB * NPS, DD, DD, BB * NPS, 0LL, 0, 0);
  // S11: vT = ps @ Wv -> bf16
  hipLaunchKernelGGL(gemm_mfma, dim3(6, 64), dim3(256), 0, stream,
                     PSBp, WSLOT(3), (const float*)nullptr, (const float*)nullptr,
                     (float*)nullptr, 1, VTp, DD, 0,
                     BB * NPS, DD, DD, BB * NPS, 0LL, 0, 0);
  // S12: stage-2 attention (MFMA) -> sa bf16
  hipLaunchKernelGGL((attn_mfma<NPS, 8, 0, 0>), dim3(BB * HH, 2), dim3(512), 0, stream,
                     QT2p, DD, LK, 0,
                     (const void*)KTp, DD,
                     VTp, DD,
                     SAp, DD, LK, 0,
                     (float*)nullptr, LK);
  // S13: s2 = s + sa @ Wtp + btp (into x2 rows 64..243)
  hipLaunchKernelGGL(gemm_mfma, dim3(6, 45), dim3(256), 0, stream,
                     SAp, WSLOT(4), btp, wsf + OFF_X2,
                     wsf + OFF_X2, DD, (unsigned short*)nullptr, 1, DD,
                     BB * LK, DD, DD, LK, (long long)244 * DD, NT, 0);
  // S14: h2 = LN(x2) -> bf16
  hipLaunchKernelGGL((ln_kernel<1>), dim3(BB * 244), dim3(256), 0, stream,
                     wsf + OFF_X2, (float*)nullptr, H2p, g2, b2, BB * 244, 0LL, 0);
  // S15: mid = gelu(h2 @ W1 + b1m) -> bf16
  hipLaunchKernelGGL(cvt_wt, dim3(96, 24, 1), dim3(256), 0, stream,
                     W1, WTS2, DD, 4 * DD, 0, 0, 0LL);
  hipLaunchKernelGGL(gemm_mfma, dim3(24, 61), dim3(256), 0, stream,
                     H2p, WTS2, b1m, (const float*)nullptr,
                     (float*)nullptr, 1, MIDp, 4 * DD, 0,
                     BB * 244, 4 * DD, DD, BB * 244, 0LL, 0, 1);
  // S16: x_out = x2 + mid @ W2 + b2m -> f32 d_out
  hipLaunchKernelGGL(cvt_wt, dim3(24, 96, 1), dim3(256), 0, stream,
                     W2, WTS2, 4 * DD, DD, 0, 0, 0LL);
  hipLaunchKernelGGL(gemm_mfma, dim3(6, 61), dim3(256), 0, stream,
                     MIDp, WTS2, b2m, wsf + OFF_X2,
                     out + O_X, DD, (unsigned short*)nullptr, 1, DD,
                     BB * 244, DD, 4 * DD, BB * 244, 0LL, 0, 0);
}